// Round 1
// baseline (6043.196 us; speedup 1.0000x reference)
//
#include <hip/hip_runtime.h>
#include <hip/hip_bf16.h>

#define NNODES 50000
#define NEDGES 800000

// ---------------------------------------------------------------------------
// Tiled fp32 GEMM: C[M,Ncols] = A[M,K] @ B[K,Ncols]
// 64x64 tile, 256 threads, 4x4 per thread, K-tile 16.
// ---------------------------------------------------------------------------
__global__ __launch_bounds__(256) void gemm_kernel(
    const float* __restrict__ A, const float* __restrict__ B,
    float* __restrict__ C, int M, int K, int Ncols) {
  __shared__ float As[64][17];   // [row][k], padded to dodge bank conflicts
  __shared__ float Bs[16][64];   // [k][col]

  int t  = threadIdx.x;
  int tx = t & 15, ty = t >> 4;
  int row0 = blockIdx.y * 64;
  int col0 = blockIdx.x * 64;

  float acc[4][4] = {};

  for (int k0 = 0; k0 < K; k0 += 16) {
    // load A tile: 64 rows x 16 k (coalesced along k)
    {
      int kk = t & 15, r = t >> 4;
      #pragma unroll
      for (int p = 0; p < 4; ++p) {
        int row = row0 + r + p * 16;
        As[r + p * 16][kk] = (row < M) ? A[(size_t)row * K + k0 + kk] : 0.f;
      }
    }
    // load B tile: 16 k x 64 cols (coalesced along col)
    {
      int col = t & 63, kk = t >> 6;
      #pragma unroll
      for (int p = 0; p < 4; ++p) {
        Bs[kk + p * 4][col] = B[(size_t)(k0 + kk + p * 4) * Ncols + col0 + col];
      }
    }
    __syncthreads();
    #pragma unroll
    for (int kk = 0; kk < 16; ++kk) {
      float a[4], b[4];
      #pragma unroll
      for (int i = 0; i < 4; ++i) a[i] = As[ty * 4 + i][kk];
      #pragma unroll
      for (int j = 0; j < 4; ++j) b[j] = Bs[kk][tx * 4 + j];
      #pragma unroll
      for (int i = 0; i < 4; ++i)
        #pragma unroll
        for (int j = 0; j < 4; ++j) acc[i][j] += a[i] * b[j];
    }
    __syncthreads();
  }

  #pragma unroll
  for (int i = 0; i < 4; ++i) {
    int row = row0 + ty * 4 + i;
    if (row >= M) break;
    #pragma unroll
    for (int j = 0; j < 4; ++j)
      C[(size_t)row * Ncols + col0 + tx * 4 + j] = acc[i][j];
  }
}

// ---------------------------------------------------------------------------
// alpha_src[n,h] = sum_c h[n,h,c]*a_src[h,c] ; same for dst. Thread per (n,h).
// ---------------------------------------------------------------------------
__global__ void alpha_kernel(const float* __restrict__ h,
                             const float* __restrict__ a_src,
                             const float* __restrict__ a_dst,
                             float* __restrict__ as_out, float* __restrict__ ad_out,
                             int n, int H, int C) {
  int idx = blockIdx.x * blockDim.x + threadIdx.x;
  if (idx >= n * H) return;
  int node = idx / H, hd = idx % H;
  const float* hp = h + (size_t)node * H * C + hd * C;
  float s1 = 0.f, s2 = 0.f;
  for (int c = 0; c < C; ++c) {
    float v = hp[c];
    s1 += v * a_src[hd * C + c];
    s2 += v * a_dst[hd * C + c];
  }
  as_out[idx] = s1;
  ad_out[idx] = s2;
}

// ---------------------------------------------------------------------------
// Pass 1 over edges: denom[d,h] += exp(leaky_relu(as[s,h]+ad[d,h]))
// (segment_max skipped: softmax is shift-invariant and logits are bounded here)
// ---------------------------------------------------------------------------
__global__ void edge_denom_kernel(const int* __restrict__ src, const int* __restrict__ dst,
                                  const float* __restrict__ as_, const float* __restrict__ ad_,
                                  float* __restrict__ denom, int E, int H) {
  int idx = blockIdx.x * blockDim.x + threadIdx.x;
  if (idx >= E * H) return;
  int e = idx / H, hd = idx - e * H;
  int s = src[e], d = dst[e];
  float l = as_[s * H + hd] + ad_[d * H + hd];
  l = (l > 0.f) ? l : 0.2f * l;
  float ev = __expf(l);
  unsafeAtomicAdd(&denom[d * H + hd], ev);
}

// ---------------------------------------------------------------------------
// Pass 2 over edges: agg[d, :] += alpha * h[s, :]. One wave per edge.
// HC = H*C total channels (256 for layers 1/2, 64 for layer 3).
// ---------------------------------------------------------------------------
template <int HC, int C>
__global__ __launch_bounds__(256) void edge_aggr_kernel(
    const int* __restrict__ src, const int* __restrict__ dst,
    const float* __restrict__ h, const float* __restrict__ as_,
    const float* __restrict__ ad_, const float* __restrict__ denom,
    float* __restrict__ agg, int E, int H) {
  int e = blockIdx.x * 4 + (threadIdx.x >> 6);
  if (e >= E) return;
  int lane = threadIdx.x & 63;
  int s = src[e], d = dst[e];
  constexpr int PER = HC / 64;
  int c0 = lane * PER;
  int hd = c0 / C;
  float l = as_[s * H + hd] + ad_[d * H + hd];
  l = (l > 0.f) ? l : 0.2f * l;
  float ev = __expf(l);
  float alpha = ev / (denom[d * H + hd] + 1e-16f);
  const float* hs = h + (size_t)s * HC + c0;
  float* ag = agg + (size_t)d * HC + c0;
  if (PER == 4) {
    float4 v = *(const float4*)hs;
    unsafeAtomicAdd(ag + 0, alpha * v.x);
    unsafeAtomicAdd(ag + 1, alpha * v.y);
    unsafeAtomicAdd(ag + 2, alpha * v.z);
    unsafeAtomicAdd(ag + 3, alpha * v.w);
  } else {
    unsafeAtomicAdd(ag, alpha * hs[0]);
  }
}

// ---------------------------------------------------------------------------
// out = agg + b, optional ELU. In-place safe (outbuf may == agg).
// ---------------------------------------------------------------------------
__global__ void finalize_kernel(const float* __restrict__ agg, const float* __restrict__ b,
                                float* __restrict__ outbuf, int n, int HC, int do_elu) {
  int idx = blockIdx.x * blockDim.x + threadIdx.x;
  if (idx >= n * HC) return;
  int c = idx % HC;
  float v = agg[idx] + b[c];
  if (do_elu) v = (v > 0.f) ? v : expm1f(v);
  outbuf[idx] = v;
}

// ---------------------------------------------------------------------------

extern "C" void kernel_launch(void* const* d_in, const int* in_sizes, int n_in,
                              void* d_out, int out_size, void* d_ws, size_t ws_size,
                              hipStream_t stream) {
  const float* x   = (const float*)d_in[0];
  const int*   ei  = (const int*)d_in[1];
  const float* W1  = (const float*)d_in[2];
  const float* aS1 = (const float*)d_in[3];
  const float* aD1 = (const float*)d_in[4];
  const float* b1  = (const float*)d_in[5];
  const float* W2  = (const float*)d_in[6];
  const float* aS2 = (const float*)d_in[7];
  const float* aD2 = (const float*)d_in[8];
  const float* b2  = (const float*)d_in[9];
  const float* W3  = (const float*)d_in[10];
  const float* aS3 = (const float*)d_in[11];
  const float* aD3 = (const float*)d_in[12];
  const float* b3  = (const float*)d_in[13];

  const int* srcp = ei;            // edge_index row 0
  const int* dstp = ei + NEDGES;   // edge_index row 1

  // workspace layout (~107 MB)
  float* bufA  = (float*)d_ws;                       // h buffer:   N*256
  float* bufB  = bufA + (size_t)NNODES * 256;        // agg/feat:   N*256
  float* as_   = bufB + (size_t)NNODES * 256;        // N*8
  float* ad_   = as_ + (size_t)NNODES * 8;           // N*8
  float* denom = ad_ + (size_t)NNODES * 8;           // N*8
  float* outp  = (float*)d_out;

  auto run_layer = [&](const float* feat_in, int K, const float* W,
                       const float* av_s, const float* av_d, const float* b,
                       int H, int C, float* h_buf, float* agg_buf, float* final_buf,
                       bool do_elu) {
    int HC = H * C;
    // GEMM h = feat_in @ W
    dim3 grid((HC + 63) / 64, (NNODES + 63) / 64);
    gemm_kernel<<<grid, 256, 0, stream>>>(feat_in, W, h_buf, NNODES, K, HC);
    // attention coefficients
    int t1 = NNODES * H;
    alpha_kernel<<<(t1 + 255) / 256, 256, 0, stream>>>(h_buf, av_s, av_d, as_, ad_,
                                                       NNODES, H, C);
    // zero accumulators
    hipMemsetAsync(denom, 0, (size_t)NNODES * H * sizeof(float), stream);
    hipMemsetAsync(agg_buf, 0, (size_t)NNODES * HC * sizeof(float), stream);
    // softmax denominator
    int t2 = NEDGES * H;
    edge_denom_kernel<<<(t2 + 255) / 256, 256, 0, stream>>>(srcp, dstp, as_, ad_,
                                                            denom, NEDGES, H);
    // weighted scatter-aggregate
    if (HC == 256)
      edge_aggr_kernel<256, 32><<<NEDGES / 4, 256, 0, stream>>>(
          srcp, dstp, h_buf, as_, ad_, denom, agg_buf, NEDGES, H);
    else
      edge_aggr_kernel<64, 64><<<NEDGES / 4, 256, 0, stream>>>(
          srcp, dstp, h_buf, as_, ad_, denom, agg_buf, NEDGES, H);
    // bias + activation
    int t3 = NNODES * HC;
    finalize_kernel<<<(t3 + 255) / 256, 256, 0, stream>>>(agg_buf, b, final_buf,
                                                          NNODES, HC, do_elu ? 1 : 0);
  };

  // layer 1: x[N,128] -> feat in bufB [N,256]
  run_layer(x, 128, W1, aS1, aD1, b1, 8, 32, bufA, bufB, bufB, true);
  // layer 2: bufB -> bufB (h in bufA; agg overwrites bufB after GEMM consumed it)
  run_layer(bufB, 256, W2, aS2, aD2, b2, 8, 32, bufA, bufB, bufB, true);
  // layer 3: bufB -> d_out [N,64], no ELU (heads=1, mean over 1 head = identity)
  run_layer(bufB, 256, W3, aS3, aD3, b3, 1, 64, bufA, outp, outp, false);
}

// Round 2
// 778.530 us; speedup vs baseline: 7.7623x; 7.7623x over previous
//
#include <hip/hip_runtime.h>
#include <hip/hip_bf16.h>

#define NNODES 50000
#define NEDGES 800000

// ---------------------------------------------------------------------------
// Tiled fp32 GEMM: C[M,Ncols] = A[M,K] @ B[K,Ncols]
// 64x64 tile, 256 threads, 4x4 per thread, K-tile 16.
// ---------------------------------------------------------------------------
__global__ __launch_bounds__(256) void gemm_kernel(
    const float* __restrict__ A, const float* __restrict__ B,
    float* __restrict__ C, int M, int K, int Ncols) {
  __shared__ float As[64][17];
  __shared__ float Bs[16][64];

  int t  = threadIdx.x;
  int tx = t & 15, ty = t >> 4;
  int row0 = blockIdx.y * 64;
  int col0 = blockIdx.x * 64;

  float acc[4][4] = {};

  for (int k0 = 0; k0 < K; k0 += 16) {
    {
      int kk = t & 15, r = t >> 4;
      #pragma unroll
      for (int p = 0; p < 4; ++p) {
        int row = row0 + r + p * 16;
        As[r + p * 16][kk] = (row < M) ? A[(size_t)row * K + k0 + kk] : 0.f;
      }
    }
    {
      int col = t & 63, kk = t >> 6;
      #pragma unroll
      for (int p = 0; p < 4; ++p) {
        Bs[kk + p * 4][col] = B[(size_t)(k0 + kk + p * 4) * Ncols + col0 + col];
      }
    }
    __syncthreads();
    #pragma unroll
    for (int kk = 0; kk < 16; ++kk) {
      float a[4], b[4];
      #pragma unroll
      for (int i = 0; i < 4; ++i) a[i] = As[ty * 4 + i][kk];
      #pragma unroll
      for (int j = 0; j < 4; ++j) b[j] = Bs[kk][tx * 4 + j];
      #pragma unroll
      for (int i = 0; i < 4; ++i)
        #pragma unroll
        for (int j = 0; j < 4; ++j) acc[i][j] += a[i] * b[j];
    }
    __syncthreads();
  }

  #pragma unroll
  for (int i = 0; i < 4; ++i) {
    int row = row0 + ty * 4 + i;
    if (row >= M) break;
    #pragma unroll
    for (int j = 0; j < 4; ++j)
      C[(size_t)row * Ncols + col0 + tx * 4 + j] = acc[i][j];
  }
}

// ---------------------------------------------------------------------------
// alpha_src[n,h] = sum_c h[n,h,c]*a_src[h,c] ; same for dst. Thread per (n,h).
// ---------------------------------------------------------------------------
__global__ void alpha_kernel(const float* __restrict__ h,
                             const float* __restrict__ a_src,
                             const float* __restrict__ a_dst,
                             float* __restrict__ as_out, float* __restrict__ ad_out,
                             int n, int H, int C) {
  int idx = blockIdx.x * blockDim.x + threadIdx.x;
  if (idx >= n * H) return;
  int node = idx / H, hd = idx % H;
  const float* hp = h + (size_t)node * H * C + hd * C;
  float s1 = 0.f, s2 = 0.f;
  for (int c = 0; c < C; ++c) {
    float v = hp[c];
    s1 += v * a_src[hd * C + c];
    s2 += v * a_dst[hd * C + c];
  }
  as_out[idx] = s1;
  ad_out[idx] = s2;
}

// ---------------------------------------------------------------------------
// CSR build: in-degree count -> exclusive scan -> scatter src ids by dst.
// ---------------------------------------------------------------------------
__global__ void deg_kernel(const int* __restrict__ dst, int* __restrict__ deg, int E) {
  int e = blockIdx.x * blockDim.x + threadIdx.x;
  if (e < E) atomicAdd(&deg[dst[e]], 1);
}

// Each block: 256 threads x 4 elems = 1024. Writes exclusive-scanned chunk +
// block total.
__global__ __launch_bounds__(256) void scan_partial(const int* __restrict__ deg,
                                                    int* __restrict__ rowptr,
                                                    int* __restrict__ blocksum, int n) {
  __shared__ int sdata[256];
  int t = threadIdx.x;
  int base = blockIdx.x * 1024 + t * 4;
  int v[4], s = 0;
  #pragma unroll
  for (int i = 0; i < 4; ++i) {
    v[i] = (base + i < n) ? deg[base + i] : 0;
    s += v[i];
  }
  sdata[t] = s;
  __syncthreads();
  for (int off = 1; off < 256; off <<= 1) {
    int x = (t >= off) ? sdata[t - off] : 0;
    __syncthreads();
    sdata[t] += x;
    __syncthreads();
  }
  int run = sdata[t] - s;  // exclusive prefix of this thread within block
  #pragma unroll
  for (int i = 0; i < 4; ++i) {
    if (base + i < n) rowptr[base + i] = run;
    run += v[i];
  }
  if (t == 255) blocksum[blockIdx.x] = sdata[255];
}

__global__ __launch_bounds__(256) void scan_blocksums(int* __restrict__ blocksum, int nb) {
  __shared__ int sdata[256];
  int t = threadIdx.x;
  int v = (t < nb) ? blocksum[t] : 0;
  sdata[t] = v;
  __syncthreads();
  for (int off = 1; off < 256; off <<= 1) {
    int x = (t >= off) ? sdata[t - off] : 0;
    __syncthreads();
    sdata[t] += x;
    __syncthreads();
  }
  if (t < nb) blocksum[t] = sdata[t] - v;  // exclusive
}

__global__ void scan_add(int* __restrict__ rowptr, const int* __restrict__ blocksum,
                         int n, int E) {
  int idx = blockIdx.x * blockDim.x + threadIdx.x;
  if (idx < n) rowptr[idx] += blocksum[idx >> 10];
  if (idx == n) rowptr[n] = E;
}

__global__ void scatter_kernel(const int* __restrict__ src, const int* __restrict__ dst,
                               const int* __restrict__ rowptr, int* __restrict__ cursor,
                               int* __restrict__ col_src, int E) {
  int e = blockIdx.x * blockDim.x + threadIdx.x;
  if (e >= E) return;
  int d = dst[e];
  int pos = rowptr[d] + atomicAdd(&cursor[d], 1);
  col_src[pos] = src[e];
}

// ---------------------------------------------------------------------------
// One wave per dst node: fused softmax + weighted aggregate + bias + ELU.
// out[d,:] = ELU( (sum_e exp(l_e) * h[src_e,:]) / (sum_e exp(l_e) + eps) + b )
// ---------------------------------------------------------------------------
template <int HC, int C>
__global__ __launch_bounds__(256) void dst_aggr_kernel(
    const int* __restrict__ rowptr, const int* __restrict__ col_src,
    const float* __restrict__ h, const float* __restrict__ as_,
    const float* __restrict__ ad_, const float* __restrict__ bias,
    float* __restrict__ outp, int n, int do_elu) {
  constexpr int H = HC / C;
  constexpr int PER = HC / 64;
  int d = blockIdx.x * 4 + (threadIdx.x >> 6);
  if (d >= n) return;
  int lane = threadIdx.x & 63;
  int c0 = lane * PER;
  int hd = c0 / C;
  float ad_d = ad_[d * H + hd];
  float acc[PER] = {};
  float denom = 0.f;
  int beg = rowptr[d], end = rowptr[d + 1];
  for (int i = beg; i < end; ++i) {
    int s = col_src[i];
    float l = as_[s * H + hd] + ad_d;
    l = (l > 0.f) ? l : 0.2f * l;
    float ev = __expf(l);
    denom += ev;
    const float* hp = h + (size_t)s * HC + c0;
    if (PER == 4) {
      float4 v = *(const float4*)hp;
      acc[0] += ev * v.x;
      acc[1] += ev * v.y;
      acc[2] += ev * v.z;
      acc[3] += ev * v.w;
    } else {
      acc[0] += ev * hp[0];
    }
  }
  float inv = 1.f / (denom + 1e-16f);
  #pragma unroll
  for (int j = 0; j < PER; ++j) {
    float v = acc[j] * inv + bias[c0 + j];
    if (do_elu) v = (v > 0.f) ? v : expm1f(v);
    outp[(size_t)d * HC + c0 + j] = v;
  }
}

// ---------------------------------------------------------------------------

extern "C" void kernel_launch(void* const* d_in, const int* in_sizes, int n_in,
                              void* d_out, int out_size, void* d_ws, size_t ws_size,
                              hipStream_t stream) {
  const float* x   = (const float*)d_in[0];
  const int*   ei  = (const int*)d_in[1];
  const float* W1  = (const float*)d_in[2];
  const float* aS1 = (const float*)d_in[3];
  const float* aD1 = (const float*)d_in[4];
  const float* b1  = (const float*)d_in[5];
  const float* W2  = (const float*)d_in[6];
  const float* aS2 = (const float*)d_in[7];
  const float* aD2 = (const float*)d_in[8];
  const float* b2  = (const float*)d_in[9];
  const float* W3  = (const float*)d_in[10];
  const float* aS3 = (const float*)d_in[11];
  const float* aD3 = (const float*)d_in[12];
  const float* b3  = (const float*)d_in[13];

  const int* srcp = ei;
  const int* dstp = ei + NEDGES;

  // workspace layout (~109 MB)
  float* bufA   = (float*)d_ws;                     // h buffer:   N*256 f
  float* bufB   = bufA + (size_t)NNODES * 256;      // feat:       N*256 f
  float* as_    = bufB + (size_t)NNODES * 256;      // N*8 f
  float* ad_    = as_ + (size_t)NNODES * 8;         // N*8 f
  int*   rowptr = (int*)(ad_ + (size_t)NNODES * 8); // N+1 i
  int*   cursor = rowptr + (NNODES + 1);            // N i (deg, then cursor)
  int*   colsrc = cursor + NNODES;                  // E i
  int*   bsum   = colsrc + NEDGES;                  // 256 i
  float* outp   = (float*)d_out;

  // ---- CSR build (once; edge structure shared by all 3 layers) ----
  hipMemsetAsync(cursor, 0, NNODES * sizeof(int), stream);
  deg_kernel<<<(NEDGES + 255) / 256, 256, 0, stream>>>(dstp, cursor, NEDGES);
  int nb = (NNODES + 1023) / 1024;  // 49
  scan_partial<<<nb, 256, 0, stream>>>(cursor, rowptr, bsum, NNODES);
  scan_blocksums<<<1, 256, 0, stream>>>(bsum, nb);
  scan_add<<<(NNODES + 256) / 256, 256, 0, stream>>>(rowptr, bsum, NNODES, NEDGES);
  hipMemsetAsync(cursor, 0, NNODES * sizeof(int), stream);
  scatter_kernel<<<(NEDGES + 255) / 256, 256, 0, stream>>>(srcp, dstp, rowptr, cursor,
                                                           colsrc, NEDGES);

  auto run_layer = [&](const float* feat_in, int K, const float* W,
                       const float* av_s, const float* av_d, const float* b,
                       int H, int C, float* h_buf, float* final_buf, bool do_elu) {
    int HC = H * C;
    dim3 grid((HC + 63) / 64, (NNODES + 63) / 64);
    gemm_kernel<<<grid, 256, 0, stream>>>(feat_in, W, h_buf, NNODES, K, HC);
    int t1 = NNODES * H;
    alpha_kernel<<<(t1 + 255) / 256, 256, 0, stream>>>(h_buf, av_s, av_d, as_, ad_,
                                                       NNODES, H, C);
    int gb = (NNODES + 3) / 4;
    if (HC == 256)
      dst_aggr_kernel<256, 32><<<gb, 256, 0, stream>>>(rowptr, colsrc, h_buf, as_, ad_,
                                                       b, final_buf, NNODES, do_elu);
    else
      dst_aggr_kernel<64, 64><<<gb, 256, 0, stream>>>(rowptr, colsrc, h_buf, as_, ad_,
                                                      b, final_buf, NNODES, do_elu);
  };

  // layer 1: x[N,128] -> bufB [N,256]
  run_layer(x, 128, W1, aS1, aD1, b1, 8, 32, bufA, bufB, true);
  // layer 2: bufB -> bufB (h in bufA; aggregate overwrites bufB)
  run_layer(bufB, 256, W2, aS2, aD2, b2, 8, 32, bufA, bufB, true);
  // layer 3: bufB -> d_out [N,64] (heads=1, mean == identity), no ELU
  run_layer(bufB, 256, W3, aS3, aD3, b3, 1, 64, bufA, outp, false);
}

// Round 3
// 425.098 us; speedup vs baseline: 14.2160x; 1.8314x over previous
//
#include <hip/hip_runtime.h>
#include <hip/hip_bf16.h>
#include <stdint.h>

#define NNODES 50000
#define NEDGES 800000

typedef float f32x4 __attribute__((ext_vector_type(4)));
typedef short short8 __attribute__((ext_vector_type(8)));

__device__ __forceinline__ ushort f2bf(float f) {
  uint32_t u = __float_as_uint(f);
  u += 0x7fff + ((u >> 16) & 1);   // RNE
  return (ushort)(u >> 16);
}
__device__ __forceinline__ float bf2f(ushort h) {
  return __uint_as_float(((uint32_t)h) << 16);
}
__device__ __forceinline__ float bflo(uint32_t u) { return __uint_as_float(u << 16); }
__device__ __forceinline__ float bfhi(uint32_t u) { return __uint_as_float(u & 0xffff0000u); }

__device__ __forceinline__ void gload_lds16(const void* g, void* l) {
  __builtin_amdgcn_global_load_lds(
      (const __attribute__((address_space(1))) uint32_t*)g,
      (__attribute__((address_space(3))) uint32_t*)l, 16, 0, 0);
}

// ---------------------------------------------------------------------------
// Split-bf16 MFMA GEMM: C = (Ah+Al) @ (Bh+Bl)^T-stored, dropping Al*Bl.
// A: [M][K] bf16 hi/lo. B given as Wt[N][K] bf16 hi/lo (pre-transposed).
// BM=128, BN=64, BK=64; 4 waves (2x2); 16x16x32 bf16 MFMA; fp32 accum.
// LDS rows are 128B; XOR slot swizzle (slot ^= row&7) on both stage-src and
// ds_read (rule #21: linear LDS dest for global_load_lds, pre-swizzled src).
// OUTBF=1: store bf16; OUTBF=0: store fp32.
// ---------------------------------------------------------------------------
template <int OUTBF>
__global__ __launch_bounds__(256) void gemm_mfma(
    const ushort* __restrict__ Ah, const ushort* __restrict__ Al,
    const ushort* __restrict__ Bh, const ushort* __restrict__ Bl,
    void* __restrict__ Cout, int M, int K, int Ncols) {
  __shared__ ushort AsH[128 * 64];
  __shared__ ushort AsL[128 * 64];
  __shared__ ushort BsH[64 * 64];
  __shared__ ushort BsL[64 * 64];

  const int t = threadIdx.x;
  const int w = t >> 6, ln = t & 63;
  const int row0 = blockIdx.y * 128;
  const int col0 = blockIdx.x * 64;
  const int wr = (w >> 1) * 64, wc = (w & 1) * 32;

  f32x4 acc[4][2] = {};

  const int nkt = K >> 6;
  for (int kt = 0; kt < nkt; ++kt) {
    const int k0 = kt << 6;
    // stage A hi/lo (16KB each): 16 wave-instr per matrix, 4 per wave
    #pragma unroll
    for (int i = 0; i < 4; ++i) {
      int row8 = w * 4 + i;
      int rloc = row8 * 8 + (ln >> 3);
      int sslot = (ln & 7) ^ (rloc & 7);
      int grow = row0 + rloc; grow = grow < M ? grow : M - 1;
      size_t go = (size_t)grow * K + k0 + sslot * 8;
      gload_lds16(Ah + go, AsH + row8 * 512);
      gload_lds16(Al + go, AsL + row8 * 512);
    }
    // stage B hi/lo (8KB each): 8 wave-instr per matrix, 2 per wave
    #pragma unroll
    for (int i = 0; i < 2; ++i) {
      int row8 = w * 2 + i;
      int rloc = row8 * 8 + (ln >> 3);
      int sslot = (ln & 7) ^ (rloc & 7);
      size_t go = (size_t)(col0 + rloc) * K + k0 + sslot * 8;
      gload_lds16(Bh + go, BsH + row8 * 512);
      gload_lds16(Bl + go, BsL + row8 * 512);
    }
    __syncthreads();

    #pragma unroll
    for (int ks = 0; ks < 2; ++ks) {
      short8 ah[4], al[4], bh[2], bl[2];
      #pragma unroll
      for (int i = 0; i < 4; ++i) {
        int row = wr + i * 16 + (ln & 15);
        int slot = (ks * 4 + (ln >> 4)) ^ (row & 7);
        int off = row * 64 + slot * 8;
        ah[i] = *(const short8*)(AsH + off);
        al[i] = *(const short8*)(AsL + off);
      }
      #pragma unroll
      for (int j = 0; j < 2; ++j) {
        int col = wc + j * 16 + (ln & 15);
        int slot = (ks * 4 + (ln >> 4)) ^ (col & 7);
        int off = col * 64 + slot * 8;
        bh[j] = *(const short8*)(BsH + off);
        bl[j] = *(const short8*)(BsL + off);
      }
      #pragma unroll
      for (int i = 0; i < 4; ++i)
        #pragma unroll
        for (int j = 0; j < 2; ++j) {
          acc[i][j] = __builtin_amdgcn_mfma_f32_16x16x32_bf16(ah[i], bh[j], acc[i][j], 0, 0, 0);
          acc[i][j] = __builtin_amdgcn_mfma_f32_16x16x32_bf16(al[i], bh[j], acc[i][j], 0, 0, 0);
          acc[i][j] = __builtin_amdgcn_mfma_f32_16x16x32_bf16(ah[i], bl[j], acc[i][j], 0, 0, 0);
        }
    }
    __syncthreads();
  }

  // epilogue: C/D layout col=lane&15, row=(lane>>4)*4+reg (m89-verified)
  #pragma unroll
  for (int i = 0; i < 4; ++i)
    #pragma unroll
    for (int j = 0; j < 2; ++j)
      #pragma unroll
      for (int r = 0; r < 4; ++r) {
        int grow = row0 + wr + i * 16 + (ln >> 4) * 4 + r;
        int gcol = col0 + wc + j * 16 + (ln & 15);
        if (grow < M) {
          if (OUTBF)
            ((ushort*)Cout)[(size_t)grow * Ncols + gcol] = f2bf(acc[i][j][r]);
          else
            ((float*)Cout)[(size_t)grow * Ncols + gcol] = acc[i][j][r];
        }
      }
}

// ---------------------------------------------------------------------------
// fp32 -> bf16 hi/lo split (elementwise, float4-vectorized)
// ---------------------------------------------------------------------------
__global__ void cvt_split(const float* __restrict__ in, ushort* __restrict__ hi,
                          ushort* __restrict__ lo, int n4) {
  int idx = blockIdx.x * blockDim.x + threadIdx.x;
  if (idx >= n4) return;
  float4 v = ((const float4*)in)[idx];
  ushort4 h, l;
  h.x = f2bf(v.x); l.x = f2bf(v.x - bf2f(h.x));
  h.y = f2bf(v.y); l.y = f2bf(v.y - bf2f(h.y));
  h.z = f2bf(v.z); l.z = f2bf(v.z - bf2f(h.z));
  h.w = f2bf(v.w); l.w = f2bf(v.w - bf2f(h.w));
  ((ushort4*)hi)[idx] = h;
  ((ushort4*)lo)[idx] = l;
}

// W [K][N] fp32 -> Wt [N][K] bf16 hi/lo (tiny)
__global__ void cvt_w(const float* __restrict__ W, ushort* __restrict__ th,
                      ushort* __restrict__ tl, int K, int N) {
  int idx = blockIdx.x * blockDim.x + threadIdx.x;
  if (idx >= K * N) return;
  int k = idx / N, c = idx - k * N;
  float f = W[idx];
  ushort h = f2bf(f);
  th[(size_t)c * K + k] = h;
  tl[(size_t)c * K + k] = f2bf(f - bf2f(h));
}

// ---------------------------------------------------------------------------
// alpha coefficients from bf16 h (layers 1/2: H=8, C=32)
// ---------------------------------------------------------------------------
__global__ void alpha_bf(const ushort* __restrict__ h, const float* __restrict__ a_src,
                         const float* __restrict__ a_dst, float* __restrict__ as_out,
                         float* __restrict__ ad_out, int n) {
  int idx = blockIdx.x * blockDim.x + threadIdx.x;
  if (idx >= n * 8) return;
  int node = idx >> 3, hd = idx & 7;
  const uint32_t* hp = (const uint32_t*)(h + (size_t)node * 256 + hd * 32);
  float s1 = 0.f, s2 = 0.f;
  #pragma unroll
  for (int q = 0; q < 16; ++q) {
    uint32_t u = hp[q];
    float f0 = bflo(u), f1 = bfhi(u);
    s1 += f0 * a_src[hd * 32 + 2 * q] + f1 * a_src[hd * 32 + 2 * q + 1];
    s2 += f0 * a_dst[hd * 32 + 2 * q] + f1 * a_dst[hd * 32 + 2 * q + 1];
  }
  as_out[idx] = s1;
  ad_out[idx] = s2;
}

// alpha for layer 3 (H=1, C=64, fp32 h)
__global__ void alpha_f3(const float* __restrict__ h, const float* __restrict__ a_src,
                         const float* __restrict__ a_dst, float* __restrict__ as_out,
                         float* __restrict__ ad_out, int n) {
  int idx = blockIdx.x * blockDim.x + threadIdx.x;
  if (idx >= n) return;
  const float4* hp = (const float4*)(h + (size_t)idx * 64);
  float s1 = 0.f, s2 = 0.f;
  #pragma unroll
  for (int q = 0; q < 16; ++q) {
    float4 v = hp[q];
    s1 += v.x * a_src[4 * q] + v.y * a_src[4 * q + 1] + v.z * a_src[4 * q + 2] + v.w * a_src[4 * q + 3];
    s2 += v.x * a_dst[4 * q] + v.y * a_dst[4 * q + 1] + v.z * a_dst[4 * q + 2] + v.w * a_dst[4 * q + 3];
  }
  as_out[idx] = s1;
  ad_out[idx] = s2;
}

// ---------------------------------------------------------------------------
// CSR build
// ---------------------------------------------------------------------------
__global__ void deg_kernel(const int* __restrict__ dst, int* __restrict__ deg, int E) {
  int e = blockIdx.x * blockDim.x + threadIdx.x;
  if (e < E) atomicAdd(&deg[dst[e]], 1);
}

__global__ __launch_bounds__(256) void scan_partial(const int* __restrict__ deg,
                                                    int* __restrict__ rowptr,
                                                    int* __restrict__ blocksum, int n) {
  __shared__ int sdata[256];
  int t = threadIdx.x;
  int base = blockIdx.x * 1024 + t * 4;
  int v[4], s = 0;
  #pragma unroll
  for (int i = 0; i < 4; ++i) {
    v[i] = (base + i < n) ? deg[base + i] : 0;
    s += v[i];
  }
  sdata[t] = s;
  __syncthreads();
  for (int off = 1; off < 256; off <<= 1) {
    int x = (t >= off) ? sdata[t - off] : 0;
    __syncthreads();
    sdata[t] += x;
    __syncthreads();
  }
  int run = sdata[t] - s;
  #pragma unroll
  for (int i = 0; i < 4; ++i) {
    if (base + i < n) rowptr[base + i] = run;
    run += v[i];
  }
  if (t == 255) blocksum[blockIdx.x] = sdata[255];
}

__global__ __launch_bounds__(256) void scan_blocksums(int* __restrict__ blocksum, int nb) {
  __shared__ int sdata[256];
  int t = threadIdx.x;
  int v = (t < nb) ? blocksum[t] : 0;
  sdata[t] = v;
  __syncthreads();
  for (int off = 1; off < 256; off <<= 1) {
    int x = (t >= off) ? sdata[t - off] : 0;
    __syncthreads();
    sdata[t] += x;
    __syncthreads();
  }
  if (t < nb) blocksum[t] = sdata[t] - v;
}

__global__ void scan_add(int* __restrict__ rowptr, const int* __restrict__ blocksum,
                         int n, int E) {
  int idx = blockIdx.x * blockDim.x + threadIdx.x;
  if (idx < n) rowptr[idx] += blocksum[idx >> 10];
  if (idx == n) rowptr[n] = E;
}

__global__ void scatter_kernel(const int* __restrict__ src, const int* __restrict__ dst,
                               const int* __restrict__ rowptr, int* __restrict__ cursor,
                               int* __restrict__ col_src, int E) {
  int e = blockIdx.x * blockDim.x + threadIdx.x;
  if (e >= E) return;
  int d = dst[e];
  int pos = rowptr[d] + atomicAdd(&cursor[d], 1);
  col_src[pos] = src[e];
}

// ---------------------------------------------------------------------------
// Fused per-dst softmax + aggregate. Layers 1/2: bf16 h gather, split bf16
// hi/lo output (next layer's feat) with ELU. One wave per dst node.
// ---------------------------------------------------------------------------
__global__ __launch_bounds__(256) void aggr_bf(
    const int* __restrict__ rowptr, const int* __restrict__ col_src,
    const ushort* __restrict__ h, const float* __restrict__ as_,
    const float* __restrict__ ad_, const float* __restrict__ bias,
    ushort* __restrict__ oh, ushort* __restrict__ ol, int n) {
  int d = blockIdx.x * 4 + (threadIdx.x >> 6);
  if (d >= n) return;
  int lane = threadIdx.x & 63;
  int c0 = lane * 4;
  int hd = lane >> 3;  // c0 / 32
  float ad_d = ad_[d * 8 + hd];
  float a0 = 0.f, a1 = 0.f, a2 = 0.f, a3 = 0.f, denom = 0.f;
  int beg = rowptr[d], end = rowptr[d + 1];
  int sn = (beg < end) ? col_src[beg] : 0;
  for (int i = beg; i < end; ++i) {
    int s = sn;
    if (i + 1 < end) sn = col_src[i + 1];
    float l = as_[s * 8 + hd] + ad_d;
    l = (l > 0.f) ? l : 0.2f * l;
    float ev = __expf(l);
    denom += ev;
    uint2 v = *(const uint2*)(h + (size_t)s * 256 + c0);
    a0 += ev * bflo(v.x);
    a1 += ev * bfhi(v.x);
    a2 += ev * bflo(v.y);
    a3 += ev * bfhi(v.y);
  }
  float inv = 1.f / (denom + 1e-16f);
  float v0 = a0 * inv + bias[c0 + 0];
  float v1 = a1 * inv + bias[c0 + 1];
  float v2 = a2 * inv + bias[c0 + 2];
  float v3 = a3 * inv + bias[c0 + 3];
  v0 = (v0 > 0.f) ? v0 : expm1f(v0);
  v1 = (v1 > 0.f) ? v1 : expm1f(v1);
  v2 = (v2 > 0.f) ? v2 : expm1f(v2);
  v3 = (v3 > 0.f) ? v3 : expm1f(v3);
  ushort4 hh, ll;
  hh.x = f2bf(v0); ll.x = f2bf(v0 - bf2f(hh.x));
  hh.y = f2bf(v1); ll.y = f2bf(v1 - bf2f(hh.y));
  hh.z = f2bf(v2); ll.z = f2bf(v2 - bf2f(hh.z));
  hh.w = f2bf(v3); ll.w = f2bf(v3 - bf2f(hh.w));
  *(ushort4*)(oh + (size_t)d * 256 + c0) = hh;
  *(ushort4*)(ol + (size_t)d * 256 + c0) = ll;
}

// Layer 3: fp32 h gather (keeps final output path precise), fp32 out, no ELU.
__global__ __launch_bounds__(256) void aggr_f3(
    const int* __restrict__ rowptr, const int* __restrict__ col_src,
    const float* __restrict__ h, const float* __restrict__ as_,
    const float* __restrict__ ad_, const float* __restrict__ bias,
    float* __restrict__ outp, int n) {
  int d = blockIdx.x * 4 + (threadIdx.x >> 6);
  if (d >= n) return;
  int lane = threadIdx.x & 63;
  float ad_d = ad_[d];
  float acc = 0.f, denom = 0.f;
  int beg = rowptr[d], end = rowptr[d + 1];
  int sn = (beg < end) ? col_src[beg] : 0;
  for (int i = beg; i < end; ++i) {
    int s = sn;
    if (i + 1 < end) sn = col_src[i + 1];
    float l = as_[s] + ad_d;
    l = (l > 0.f) ? l : 0.2f * l;
    float ev = __expf(l);
    denom += ev;
    acc += ev * h[(size_t)s * 64 + lane];
  }
  outp[(size_t)d * 64 + lane] = acc / (denom + 1e-16f) + bias[lane];
}

// ---------------------------------------------------------------------------

extern "C" void kernel_launch(void* const* d_in, const int* in_sizes, int n_in,
                              void* d_out, int out_size, void* d_ws, size_t ws_size,
                              hipStream_t stream) {
  const float* x   = (const float*)d_in[0];
  const int*   ei  = (const int*)d_in[1];
  const float* W1  = (const float*)d_in[2];
  const float* aS1 = (const float*)d_in[3];
  const float* aD1 = (const float*)d_in[4];
  const float* b1  = (const float*)d_in[5];
  const float* W2  = (const float*)d_in[6];
  const float* aS2 = (const float*)d_in[7];
  const float* aD2 = (const float*)d_in[8];
  const float* b2  = (const float*)d_in[9];
  const float* W3  = (const float*)d_in[10];
  const float* aS3 = (const float*)d_in[11];
  const float* aD3 = (const float*)d_in[12];
  const float* b3  = (const float*)d_in[13];

  const int* srcp = ei;
  const int* dstp = ei + NEDGES;

  // ---- arena (~110 MB) ----
  char* base = (char*)d_ws;
  size_t o = 0;
  ushort* hbf  = (ushort*)(base + o);  float* h3 = (float*)(base + o);
  o += 25600000;                         // h: 50000*256*2 (bf16) or 50000*64*4 (f32)
  ushort* fh   = (ushort*)(base + o); o += 25600000;   // feat hi (layers 2/3 input)
  ushort* fl   = (ushort*)(base + o); o += 25600000;   // feat lo
  ushort* f1h  = (ushort*)(base + o); o += 12800000;   // layer-1 input hi
  ushort* f1l  = (ushort*)(base + o); o += 12800000;   // layer-1 input lo
  float*  as_  = (float*)(base + o);  o += 1600000;
  float*  ad_  = (float*)(base + o);  o += 1600000;
  ushort* w1h  = (ushort*)(base + o); o += 65536;      // 128*256*2
  ushort* w1l  = (ushort*)(base + o); o += 65536;
  ushort* w2h  = (ushort*)(base + o); o += 131072;     // 256*256*2
  ushort* w2l  = (ushort*)(base + o); o += 131072;
  ushort* w3h  = (ushort*)(base + o); o += 32768;      // 256*64*2
  ushort* w3l  = (ushort*)(base + o); o += 32768;
  int* rowptr  = (int*)(base + o);    o += 200016;     // (N+1)*4
  int* cursor  = (int*)(base + o);    o += 200000;
  int* colsrc  = (int*)(base + o);    o += 3200000;
  int* bsum    = (int*)(base + o);    o += 1024;
  float* outp  = (float*)d_out;

  // ---- CSR build (edge structure shared by all 3 layers) ----
  hipMemsetAsync(cursor, 0, NNODES * sizeof(int), stream);
  deg_kernel<<<(NEDGES + 255) / 256, 256, 0, stream>>>(dstp, cursor, NEDGES);
  int nb = (NNODES + 1023) / 1024;  // 49
  scan_partial<<<nb, 256, 0, stream>>>(cursor, rowptr, bsum, NNODES);
  scan_blocksums<<<1, 256, 0, stream>>>(bsum, nb);
  scan_add<<<(NNODES + 256) / 256, 256, 0, stream>>>(rowptr, bsum, NNODES, NEDGES);
  hipMemsetAsync(cursor, 0, NNODES * sizeof(int), stream);
  scatter_kernel<<<(NEDGES + 255) / 256, 256, 0, stream>>>(srcp, dstp, rowptr, cursor,
                                                           colsrc, NEDGES);

  // ---- weight / input conversions ----
  cvt_split<<<(NNODES * 128 / 4 + 255) / 256, 256, 0, stream>>>(x, f1h, f1l,
                                                                NNODES * 128 / 4);
  cvt_w<<<(128 * 256 + 255) / 256, 256, 0, stream>>>(W1, w1h, w1l, 128, 256);
  cvt_w<<<(256 * 256 + 255) / 256, 256, 0, stream>>>(W2, w2h, w2l, 256, 256);
  cvt_w<<<(256 * 64 + 255) / 256, 256, 0, stream>>>(W3, w3h, w3l, 256, 64);

  const int ga = (NNODES + 3) / 4;  // aggr grid
  // ---- layer 1: x -> fh/fl ----
  gemm_mfma<1><<<dim3(4, (NNODES + 127) / 128), 256, 0, stream>>>(
      f1h, f1l, w1h, w1l, hbf, NNODES, 128, 256);
  alpha_bf<<<(NNODES * 8 + 255) / 256, 256, 0, stream>>>(hbf, aS1, aD1, as_, ad_, NNODES);
  aggr_bf<<<ga, 256, 0, stream>>>(rowptr, colsrc, hbf, as_, ad_, b1, fh, fl, NNODES);
  // ---- layer 2: fh/fl -> fh/fl (in-place ping: feat dead before aggr writes) ----
  gemm_mfma<1><<<dim3(4, (NNODES + 127) / 128), 256, 0, stream>>>(
      fh, fl, w2h, w2l, hbf, NNODES, 256, 256);
  alpha_bf<<<(NNODES * 8 + 255) / 256, 256, 0, stream>>>(hbf, aS2, aD2, as_, ad_, NNODES);
  aggr_bf<<<ga, 256, 0, stream>>>(rowptr, colsrc, hbf, as_, ad_, b2, fh, fl, NNODES);
  // ---- layer 3: fh/fl -> d_out (fp32 h, fp32 path) ----
  gemm_mfma<0><<<dim3(1, (NNODES + 127) / 128), 256, 0, stream>>>(
      fh, fl, w3h, w3l, h3, NNODES, 256, 64);
  alpha_f3<<<(NNODES + 255) / 256, 256, 0, stream>>>(h3, aS3, aD3, as_, ad_, NNODES);
  aggr_f3<<<ga, 256, 0, stream>>>(rowptr, colsrc, h3, as_, ad_, b3, outp, NNODES);
}

// Round 4
// 424.218 us; speedup vs baseline: 14.2455x; 1.0021x over previous
//
#include <hip/hip_runtime.h>
#include <hip/hip_bf16.h>
#include <stdint.h>

#define NNODES 50000
#define NEDGES 800000

typedef float f32x4 __attribute__((ext_vector_type(4)));
typedef short short8 __attribute__((ext_vector_type(8)));

__device__ __forceinline__ ushort f2bf(float f) {
  uint32_t u = __float_as_uint(f);
  u += 0x7fff + ((u >> 16) & 1);   // RNE
  return (ushort)(u >> 16);
}
__device__ __forceinline__ float bf2f(ushort h) {
  return __uint_as_float(((uint32_t)h) << 16);
}
__device__ __forceinline__ float bflo(uint32_t u) { return __uint_as_float(u << 16); }
__device__ __forceinline__ float bfhi(uint32_t u) { return __uint_as_float(u & 0xffff0000u); }

__device__ __forceinline__ void gload_lds16(const void* g, void* l) {
  __builtin_amdgcn_global_load_lds(
      (const __attribute__((address_space(1))) uint32_t*)g,
      (__attribute__((address_space(3))) uint32_t*)l, 16, 0, 0);
}

// ---------------------------------------------------------------------------
// Wide split-bf16 MFMA GEMM for layers 1/2: C[M,256] = (Ah+Al)@(Wh+Wl)^T
// BM=64, BN=256 (full width -> A panel read exactly ONCE), BK=32.
// 4 waves (2 row x 2 col), wave tile 32x128. 3-term split, fp32 accum.
// XOR swizzle slot^=(row^(row>>2))&3 on both stage-source and ds_read
// (rule #21: linear LDS dest for global_load_lds, pre-swizzled global src).
// Output bf16.
// ---------------------------------------------------------------------------
__global__ __launch_bounds__(256) void gemm_wide(
    const ushort* __restrict__ Ah, const ushort* __restrict__ Al,
    const ushort* __restrict__ Bh, const ushort* __restrict__ Bl,
    ushort* __restrict__ Cout, int M, int K) {
  __shared__ ushort AsH[64 * 32];
  __shared__ ushort AsL[64 * 32];
  __shared__ ushort BsH[256 * 32];
  __shared__ ushort BsL[256 * 32];

  const int t = threadIdx.x;
  const int w = t >> 6, ln = t & 63;
  const int row0 = blockIdx.x * 64;
  const int wr = (w >> 1) * 32, wc = (w & 1) * 128;

  f32x4 acc[2][8] = {};

  const int nkt = K >> 5;
  for (int kt = 0; kt < nkt; ++kt) {
    const int k0 = kt << 5;
    // stage A hi/lo: 64 rows x 32 k = 4KB per matrix = 1 wave-instr per wave.
    {
      int rloc = w * 16 + (ln >> 2);
      int sl = ln & 3;
      int sg = sl ^ ((rloc ^ (rloc >> 2)) & 3);
      int grow = row0 + rloc; grow = grow < M ? grow : M - 1;
      size_t go = (size_t)grow * K + k0 + sg * 8;
      gload_lds16(Ah + go, AsH + w * 512);
      gload_lds16(Al + go, AsL + w * 512);
    }
    // stage B hi/lo: 256 rows(cols of C) x 32 k = 16KB per matrix = 4/wave.
    #pragma unroll
    for (int i = 0; i < 4; ++i) {
      int rloc = w * 64 + i * 16 + (ln >> 2);
      int sl = ln & 3;
      int sg = sl ^ ((rloc ^ (rloc >> 2)) & 3);
      size_t go = (size_t)rloc * K + k0 + sg * 8;
      gload_lds16(Bh + go, BsH + (w * 64 + i * 16) * 32);
      gload_lds16(Bl + go, BsL + (w * 64 + i * 16) * 32);
    }
    __syncthreads();

    short8 ah[2], al[2], bh[8], bl[8];
    #pragma unroll
    for (int i = 0; i < 2; ++i) {
      int row = wr + i * 16 + (ln & 15);
      int slot = (ln >> 4) ^ ((row ^ (row >> 2)) & 3);
      int off = row * 32 + slot * 8;
      ah[i] = *(const short8*)(AsH + off);
      al[i] = *(const short8*)(AsL + off);
    }
    #pragma unroll
    for (int j = 0; j < 8; ++j) {
      int col = wc + j * 16 + (ln & 15);
      int slot = (ln >> 4) ^ ((col ^ (col >> 2)) & 3);
      int off = col * 32 + slot * 8;
      bh[j] = *(const short8*)(BsH + off);
      bl[j] = *(const short8*)(BsL + off);
    }
    #pragma unroll
    for (int i = 0; i < 2; ++i)
      #pragma unroll
      for (int j = 0; j < 8; ++j) {
        acc[i][j] = __builtin_amdgcn_mfma_f32_16x16x32_bf16(ah[i], bh[j], acc[i][j], 0, 0, 0);
        acc[i][j] = __builtin_amdgcn_mfma_f32_16x16x32_bf16(al[i], bh[j], acc[i][j], 0, 0, 0);
        acc[i][j] = __builtin_amdgcn_mfma_f32_16x16x32_bf16(ah[i], bl[j], acc[i][j], 0, 0, 0);
      }
    __syncthreads();
  }

  // epilogue: C/D layout col=lane&15, row=(lane>>4)*4+reg (m89-verified)
  #pragma unroll
  for (int i = 0; i < 2; ++i)
    #pragma unroll
    for (int j = 0; j < 8; ++j)
      #pragma unroll
      for (int r = 0; r < 4; ++r) {
        int grow = row0 + wr + i * 16 + (ln >> 4) * 4 + r;
        int gcol = wc + j * 16 + (ln & 15);
        if (grow < M) Cout[(size_t)grow * 256 + gcol] = f2bf(acc[i][j][r]);
      }
}

// ---------------------------------------------------------------------------
// Narrow split-bf16 MFMA GEMM (layer 3, Ncols=64): BM=128, BN=64, BK=64.
// fp32 output. (grid.x=1 -> no A re-read.)
// ---------------------------------------------------------------------------
__global__ __launch_bounds__(256) void gemm_mfma3(
    const ushort* __restrict__ Ah, const ushort* __restrict__ Al,
    const ushort* __restrict__ Bh, const ushort* __restrict__ Bl,
    float* __restrict__ Cout, int M, int K, int Ncols) {
  __shared__ ushort AsH[128 * 64];
  __shared__ ushort AsL[128 * 64];
  __shared__ ushort BsH[64 * 64];
  __shared__ ushort BsL[64 * 64];

  const int t = threadIdx.x;
  const int w = t >> 6, ln = t & 63;
  const int row0 = blockIdx.y * 128;
  const int col0 = blockIdx.x * 64;
  const int wr = (w >> 1) * 64, wc = (w & 1) * 32;

  f32x4 acc[4][2] = {};

  const int nkt = K >> 6;
  for (int kt = 0; kt < nkt; ++kt) {
    const int k0 = kt << 6;
    #pragma unroll
    for (int i = 0; i < 4; ++i) {
      int row8 = w * 4 + i;
      int rloc = row8 * 8 + (ln >> 3);
      int sslot = (ln & 7) ^ (rloc & 7);
      int grow = row0 + rloc; grow = grow < M ? grow : M - 1;
      size_t go = (size_t)grow * K + k0 + sslot * 8;
      gload_lds16(Ah + go, AsH + row8 * 512);
      gload_lds16(Al + go, AsL + row8 * 512);
    }
    #pragma unroll
    for (int i = 0; i < 2; ++i) {
      int row8 = w * 2 + i;
      int rloc = row8 * 8 + (ln >> 3);
      int sslot = (ln & 7) ^ (rloc & 7);
      size_t go = (size_t)(col0 + rloc) * K + k0 + sslot * 8;
      gload_lds16(Bh + go, BsH + row8 * 512);
      gload_lds16(Bl + go, BsL + row8 * 512);
    }
    __syncthreads();

    #pragma unroll
    for (int ks = 0; ks < 2; ++ks) {
      short8 ah[4], al[4], bh[2], bl[2];
      #pragma unroll
      for (int i = 0; i < 4; ++i) {
        int row = wr + i * 16 + (ln & 15);
        int slot = (ks * 4 + (ln >> 4)) ^ (row & 7);
        int off = row * 64 + slot * 8;
        ah[i] = *(const short8*)(AsH + off);
        al[i] = *(const short8*)(AsL + off);
      }
      #pragma unroll
      for (int j = 0; j < 2; ++j) {
        int col = wc + j * 16 + (ln & 15);
        int slot = (ks * 4 + (ln >> 4)) ^ (col & 7);
        int off = col * 64 + slot * 8;
        bh[j] = *(const short8*)(BsH + off);
        bl[j] = *(const short8*)(BsL + off);
      }
      #pragma unroll
      for (int i = 0; i < 4; ++i)
        #pragma unroll
        for (int j = 0; j < 2; ++j) {
          acc[i][j] = __builtin_amdgcn_mfma_f32_16x16x32_bf16(ah[i], bh[j], acc[i][j], 0, 0, 0);
          acc[i][j] = __builtin_amdgcn_mfma_f32_16x16x32_bf16(al[i], bh[j], acc[i][j], 0, 0, 0);
          acc[i][j] = __builtin_amdgcn_mfma_f32_16x16x32_bf16(ah[i], bl[j], acc[i][j], 0, 0, 0);
        }
    }
    __syncthreads();
  }

  #pragma unroll
  for (int i = 0; i < 4; ++i)
    #pragma unroll
    for (int j = 0; j < 2; ++j)
      #pragma unroll
      for (int r = 0; r < 4; ++r) {
        int grow = row0 + wr + i * 16 + (ln >> 4) * 4 + r;
        int gcol = col0 + wc + j * 16 + (ln & 15);
        if (grow < M) Cout[(size_t)grow * Ncols + gcol] = acc[i][j][r];
      }
}

// ---------------------------------------------------------------------------
// fp32 -> bf16 hi/lo split (elementwise, float4-vectorized)
// ---------------------------------------------------------------------------
__global__ void cvt_split(const float* __restrict__ in, ushort* __restrict__ hi,
                          ushort* __restrict__ lo, int n4) {
  int idx = blockIdx.x * blockDim.x + threadIdx.x;
  if (idx >= n4) return;
  float4 v = ((const float4*)in)[idx];
  ushort4 h, l;
  h.x = f2bf(v.x); l.x = f2bf(v.x - bf2f(h.x));
  h.y = f2bf(v.y); l.y = f2bf(v.y - bf2f(h.y));
  h.z = f2bf(v.z); l.z = f2bf(v.z - bf2f(h.z));
  h.w = f2bf(v.w); l.w = f2bf(v.w - bf2f(h.w));
  ((ushort4*)hi)[idx] = h;
  ((ushort4*)lo)[idx] = l;
}

// W [K][N] fp32 -> Wt [N][K] bf16 hi/lo (tiny)
__global__ void cvt_w(const float* __restrict__ W, ushort* __restrict__ th,
                      ushort* __restrict__ tl, int K, int N) {
  int idx = blockIdx.x * blockDim.x + threadIdx.x;
  if (idx >= K * N) return;
  int k = idx / N, c = idx - k * N;
  float f = W[idx];
  ushort h = f2bf(f);
  th[(size_t)c * K + k] = h;
  tl[(size_t)c * K + k] = f2bf(f - bf2f(h));
}

// ---------------------------------------------------------------------------
// alpha coefficients from bf16 h (layers 1/2: H=8, C=32)
// ---------------------------------------------------------------------------
__global__ void alpha_bf(const ushort* __restrict__ h, const float* __restrict__ a_src,
                         const float* __restrict__ a_dst, float* __restrict__ as_out,
                         float* __restrict__ ad_out, int n) {
  int idx = blockIdx.x * blockDim.x + threadIdx.x;
  if (idx >= n * 8) return;
  int node = idx >> 3, hd = idx & 7;
  const uint32_t* hp = (const uint32_t*)(h + (size_t)node * 256 + hd * 32);
  float s1 = 0.f, s2 = 0.f;
  #pragma unroll
  for (int q = 0; q < 16; ++q) {
    uint32_t u = hp[q];
    float f0 = bflo(u), f1 = bfhi(u);
    s1 += f0 * a_src[hd * 32 + 2 * q] + f1 * a_src[hd * 32 + 2 * q + 1];
    s2 += f0 * a_dst[hd * 32 + 2 * q] + f1 * a_dst[hd * 32 + 2 * q + 1];
  }
  as_out[idx] = s1;
  ad_out[idx] = s2;
}

// alpha for layer 3 (H=1, C=64, fp32 h)
__global__ void alpha_f3(const float* __restrict__ h, const float* __restrict__ a_src,
                         const float* __restrict__ a_dst, float* __restrict__ as_out,
                         float* __restrict__ ad_out, int n) {
  int idx = blockIdx.x * blockDim.x + threadIdx.x;
  if (idx >= n) return;
  const float4* hp = (const float4*)(h + (size_t)idx * 64);
  float s1 = 0.f, s2 = 0.f;
  #pragma unroll
  for (int q = 0; q < 16; ++q) {
    float4 v = hp[q];
    s1 += v.x * a_src[4 * q] + v.y * a_src[4 * q + 1] + v.z * a_src[4 * q + 2] + v.w * a_src[4 * q + 3];
    s2 += v.x * a_dst[4 * q] + v.y * a_dst[4 * q + 1] + v.z * a_dst[4 * q + 2] + v.w * a_dst[4 * q + 3];
  }
  as_out[idx] = s1;
  ad_out[idx] = s2;
}

// ---------------------------------------------------------------------------
// CSR build
// ---------------------------------------------------------------------------
__global__ void deg_kernel(const int* __restrict__ dst, int* __restrict__ deg, int E) {
  int e = blockIdx.x * blockDim.x + threadIdx.x;
  if (e < E) atomicAdd(&deg[dst[e]], 1);
}

__global__ __launch_bounds__(256) void scan_partial(const int* __restrict__ deg,
                                                    int* __restrict__ rowptr,
                                                    int* __restrict__ blocksum, int n) {
  __shared__ int sdata[256];
  int t = threadIdx.x;
  int base = blockIdx.x * 1024 + t * 4;
  int v[4], s = 0;
  #pragma unroll
  for (int i = 0; i < 4; ++i) {
    v[i] = (base + i < n) ? deg[base + i] : 0;
    s += v[i];
  }
  sdata[t] = s;
  __syncthreads();
  for (int off = 1; off < 256; off <<= 1) {
    int x = (t >= off) ? sdata[t - off] : 0;
    __syncthreads();
    sdata[t] += x;
    __syncthreads();
  }
  int run = sdata[t] - s;
  #pragma unroll
  for (int i = 0; i < 4; ++i) {
    if (base + i < n) rowptr[base + i] = run;
    run += v[i];
  }
  if (t == 255) blocksum[blockIdx.x] = sdata[255];
}

__global__ __launch_bounds__(256) void scan_blocksums(int* __restrict__ blocksum, int nb) {
  __shared__ int sdata[256];
  int t = threadIdx.x;
  int v = (t < nb) ? blocksum[t] : 0;
  sdata[t] = v;
  __syncthreads();
  for (int off = 1; off < 256; off <<= 1) {
    int x = (t >= off) ? sdata[t - off] : 0;
    __syncthreads();
    sdata[t] += x;
    __syncthreads();
  }
  if (t < nb) blocksum[t] = sdata[t] - v;
}

__global__ void scan_add(int* __restrict__ rowptr, const int* __restrict__ blocksum,
                         int n, int E) {
  int idx = blockIdx.x * blockDim.x + threadIdx.x;
  if (idx < n) rowptr[idx] += blocksum[idx >> 10];
  if (idx == n) rowptr[n] = E;
}

__global__ void scatter_kernel(const int* __restrict__ src, const int* __restrict__ dst,
                               const int* __restrict__ rowptr, int* __restrict__ cursor,
                               int* __restrict__ col_src, int E) {
  int e = blockIdx.x * blockDim.x + threadIdx.x;
  if (e >= E) return;
  int d = dst[e];
  int pos = rowptr[d] + atomicAdd(&cursor[d], 1);
  col_src[pos] = src[e];
}

// ---------------------------------------------------------------------------
// Fused per-dst softmax + aggregate, 2-edge unrolled (two gathers in flight).
// Layers 1/2: bf16 h gather, split bf16 hi/lo output with ELU.
// ---------------------------------------------------------------------------
__global__ __launch_bounds__(256) void aggr_bf(
    const int* __restrict__ rowptr, const int* __restrict__ col_src,
    const ushort* __restrict__ h, const float* __restrict__ as_,
    const float* __restrict__ ad_, const float* __restrict__ bias,
    ushort* __restrict__ oh, ushort* __restrict__ ol, int n) {
  int d = blockIdx.x * 4 + (threadIdx.x >> 6);
  if (d >= n) return;
  int lane = threadIdx.x & 63;
  int c0 = lane * 4;
  int hd = lane >> 3;  // c0 / 32
  float ad_d = ad_[d * 8 + hd];
  float a0 = 0.f, a1 = 0.f, a2 = 0.f, a3 = 0.f, denom = 0.f;
  int beg = rowptr[d], end = rowptr[d + 1];
  int i = beg;
  for (; i + 2 <= end; i += 2) {
    int s0 = col_src[i], s1 = col_src[i + 1];
    float l0 = as_[s0 * 8 + hd] + ad_d;
    float l1 = as_[s1 * 8 + hd] + ad_d;
    uint2 v0 = *(const uint2*)(h + (size_t)s0 * 256 + c0);
    uint2 v1 = *(const uint2*)(h + (size_t)s1 * 256 + c0);
    l0 = (l0 > 0.f) ? l0 : 0.2f * l0;
    l1 = (l1 > 0.f) ? l1 : 0.2f * l1;
    float e0 = __expf(l0), e1 = __expf(l1);
    denom += e0 + e1;
    a0 += e0 * bflo(v0.x) + e1 * bflo(v1.x);
    a1 += e0 * bfhi(v0.x) + e1 * bfhi(v1.x);
    a2 += e0 * bflo(v0.y) + e1 * bflo(v1.y);
    a3 += e0 * bfhi(v0.y) + e1 * bfhi(v1.y);
  }
  if (i < end) {
    int s = col_src[i];
    float l = as_[s * 8 + hd] + ad_d;
    l = (l > 0.f) ? l : 0.2f * l;
    float ev = __expf(l);
    denom += ev;
    uint2 v = *(const uint2*)(h + (size_t)s * 256 + c0);
    a0 += ev * bflo(v.x);
    a1 += ev * bfhi(v.x);
    a2 += ev * bflo(v.y);
    a3 += ev * bfhi(v.y);
  }
  float inv = 1.f / (denom + 1e-16f);
  float v0 = a0 * inv + bias[c0 + 0];
  float v1 = a1 * inv + bias[c0 + 1];
  float v2 = a2 * inv + bias[c0 + 2];
  float v3 = a3 * inv + bias[c0 + 3];
  v0 = (v0 > 0.f) ? v0 : expm1f(v0);
  v1 = (v1 > 0.f) ? v1 : expm1f(v1);
  v2 = (v2 > 0.f) ? v2 : expm1f(v2);
  v3 = (v3 > 0.f) ? v3 : expm1f(v3);
  ushort4 hh, ll;
  hh.x = f2bf(v0); ll.x = f2bf(v0 - bf2f(hh.x));
  hh.y = f2bf(v1); ll.y = f2bf(v1 - bf2f(hh.y));
  hh.z = f2bf(v2); ll.z = f2bf(v2 - bf2f(hh.z));
  hh.w = f2bf(v3); ll.w = f2bf(v3 - bf2f(hh.w));
  *(ushort4*)(oh + (size_t)d * 256 + c0) = hh;
  *(ushort4*)(ol + (size_t)d * 256 + c0) = ll;
}

// Layer 3: fp32 h gather, fp32 out, no ELU. 2-edge unrolled.
__global__ __launch_bounds__(256) void aggr_f3(
    const int* __restrict__ rowptr, const int* __restrict__ col_src,
    const float* __restrict__ h, const float* __restrict__ as_,
    const float* __restrict__ ad_, const float* __restrict__ bias,
    float* __restrict__ outp, int n) {
  int d = blockIdx.x * 4 + (threadIdx.x >> 6);
  if (d >= n) return;
  int lane = threadIdx.x & 63;
  float ad_d = ad_[d];
  float acc = 0.f, denom = 0.f;
  int beg = rowptr[d], end = rowptr[d + 1];
  int i = beg;
  for (; i + 2 <= end; i += 2) {
    int s0 = col_src[i], s1 = col_src[i + 1];
    float l0 = as_[s0] + ad_d;
    float l1 = as_[s1] + ad_d;
    float h0 = h[(size_t)s0 * 64 + lane];
    float h1 = h[(size_t)s1 * 64 + lane];
    l0 = (l0 > 0.f) ? l0 : 0.2f * l0;
    l1 = (l1 > 0.f) ? l1 : 0.2f * l1;
    float e0 = __expf(l0), e1 = __expf(l1);
    denom += e0 + e1;
    acc += e0 * h0 + e1 * h1;
  }
  if (i < end) {
    int s = col_src[i];
    float l = as_[s] + ad_d;
    l = (l > 0.f) ? l : 0.2f * l;
    float ev = __expf(l);
    denom += ev;
    acc += ev * h[(size_t)s * 64 + lane];
  }
  outp[(size_t)d * 64 + lane] = acc / (denom + 1e-16f) + bias[lane];
}

// ---------------------------------------------------------------------------

extern "C" void kernel_launch(void* const* d_in, const int* in_sizes, int n_in,
                              void* d_out, int out_size, void* d_ws, size_t ws_size,
                              hipStream_t stream) {
  const float* x   = (const float*)d_in[0];
  const int*   ei  = (const int*)d_in[1];
  const float* W1  = (const float*)d_in[2];
  const float* aS1 = (const float*)d_in[3];
  const float* aD1 = (const float*)d_in[4];
  const float* b1  = (const float*)d_in[5];
  const float* W2  = (const float*)d_in[6];
  const float* aS2 = (const float*)d_in[7];
  const float* aD2 = (const float*)d_in[8];
  const float* b2  = (const float*)d_in[9];
  const float* W3  = (const float*)d_in[10];
  const float* aS3 = (const float*)d_in[11];
  const float* aD3 = (const float*)d_in[12];
  const float* b3  = (const float*)d_in[13];

  const int* srcp = ei;
  const int* dstp = ei + NEDGES;

  // ---- arena (~110 MB) ----
  char* base = (char*)d_ws;
  size_t o = 0;
  ushort* hbf  = (ushort*)(base + o);  float* h3 = (float*)(base + o);
  o += 25600000;                         // h: 50000*256*2 (bf16) or 50000*64*4 (f32)
  ushort* fh   = (ushort*)(base + o); o += 25600000;   // feat hi (layers 2/3 input)
  ushort* fl   = (ushort*)(base + o); o += 25600000;   // feat lo
  ushort* f1h  = (ushort*)(base + o); o += 12800000;   // layer-1 input hi
  ushort* f1l  = (ushort*)(base + o); o += 12800000;   // layer-1 input lo
  float*  as_  = (float*)(base + o);  o += 1600000;
  float*  ad_  = (float*)(base + o);  o += 1600000;
  ushort* w1h  = (ushort*)(base + o); o += 65536;      // 128*256*2
  ushort* w1l  = (ushort*)(base + o); o += 65536;
  ushort* w2h  = (ushort*)(base + o); o += 131072;     // 256*256*2
  ushort* w2l  = (ushort*)(base + o); o += 131072;
  ushort* w3h  = (ushort*)(base + o); o += 32768;      // 256*64*2
  ushort* w3l  = (ushort*)(base + o); o += 32768;
  int* rowptr  = (int*)(base + o);    o += 200016;     // (N+1)*4
  int* cursor  = (int*)(base + o);    o += 200000;
  int* colsrc  = (int*)(base + o);    o += 3200000;
  int* bsum    = (int*)(base + o);    o += 1024;
  float* outp  = (float*)d_out;

  // ---- CSR build (edge structure shared by all 3 layers) ----
  hipMemsetAsync(cursor, 0, NNODES * sizeof(int), stream);
  deg_kernel<<<(NEDGES + 255) / 256, 256, 0, stream>>>(dstp, cursor, NEDGES);
  int nb = (NNODES + 1023) / 1024;  // 49
  scan_partial<<<nb, 256, 0, stream>>>(cursor, rowptr, bsum, NNODES);
  scan_blocksums<<<1, 256, 0, stream>>>(bsum, nb);
  scan_add<<<(NNODES + 256) / 256, 256, 0, stream>>>(rowptr, bsum, NNODES, NEDGES);
  hipMemsetAsync(cursor, 0, NNODES * sizeof(int), stream);
  scatter_kernel<<<(NEDGES + 255) / 256, 256, 0, stream>>>(srcp, dstp, rowptr, cursor,
                                                           colsrc, NEDGES);

  // ---- weight / input conversions ----
  cvt_split<<<(NNODES * 128 / 4 + 255) / 256, 256, 0, stream>>>(x, f1h, f1l,
                                                                NNODES * 128 / 4);
  cvt_w<<<(128 * 256 + 255) / 256, 256, 0, stream>>>(W1, w1h, w1l, 128, 256);
  cvt_w<<<(256 * 256 + 255) / 256, 256, 0, stream>>>(W2, w2h, w2l, 256, 256);
  cvt_w<<<(256 * 64 + 255) / 256, 256, 0, stream>>>(W3, w3h, w3l, 256, 64);

  const int ga = (NNODES + 3) / 4;           // aggr grid
  const int gw = (NNODES + 63) / 64;         // gemm_wide grid
  // ---- layer 1: x -> fh/fl ----
  gemm_wide<<<gw, 256, 0, stream>>>(f1h, f1l, w1h, w1l, hbf, NNODES, 128);
  alpha_bf<<<(NNODES * 8 + 255) / 256, 256, 0, stream>>>(hbf, aS1, aD1, as_, ad_, NNODES);
  aggr_bf<<<ga, 256, 0, stream>>>(rowptr, colsrc, hbf, as_, ad_, b1, fh, fl, NNODES);
  // ---- layer 2: fh/fl -> fh/fl (in-place ping: feat dead before aggr writes) ----
  gemm_wide<<<gw, 256, 0, stream>>>(fh, fl, w2h, w2l, hbf, NNODES, 256);
  alpha_bf<<<(NNODES * 8 + 255) / 256, 256, 0, stream>>>(hbf, aS2, aD2, as_, ad_, NNODES);
  aggr_bf<<<ga, 256, 0, stream>>>(rowptr, colsrc, hbf, as_, ad_, b2, fh, fl, NNODES);
  // ---- layer 3: fh/fl -> d_out (fp32 h, fp32 path) ----
  gemm_mfma3<<<dim3(1, (NNODES + 127) / 128), 256, 0, stream>>>(
      fh, fl, w3h, w3l, h3, NNODES, 256, 64);
  alpha_f3<<<(NNODES + 255) / 256, 256, 0, stream>>>(h3, aS3, aD3, as_, ad_, NNODES);
  aggr_f3<<<ga, 256, 0, stream>>>(rowptr, colsrc, h3, as_, ad_, b3, outp, NNODES);
}

// Round 5
// 409.146 us; speedup vs baseline: 14.7703x; 1.0368x over previous
//
#include <hip/hip_runtime.h>
#include <hip/hip_bf16.h>
#include <stdint.h>

#define NNODES 50000
#define NEDGES 800000

typedef float f32x4 __attribute__((ext_vector_type(4)));
typedef short short8 __attribute__((ext_vector_type(8)));
typedef unsigned short ushort8v __attribute__((ext_vector_type(8)));

__device__ __forceinline__ ushort f2bf(float f) {
  uint32_t u = __float_as_uint(f);
  u += 0x7fff + ((u >> 16) & 1);   // RNE
  return (ushort)(u >> 16);
}
__device__ __forceinline__ float bf2f(ushort h) {
  return __uint_as_float(((uint32_t)h) << 16);
}
__device__ __forceinline__ float bflo(uint32_t u) { return __uint_as_float(u << 16); }
__device__ __forceinline__ float bfhi(uint32_t u) { return __uint_as_float(u & 0xffff0000u); }

__device__ __forceinline__ void gload_lds16(const void* g, void* l) {
  __builtin_amdgcn_global_load_lds(
      (const __attribute__((address_space(1))) uint32_t*)g,
      (__attribute__((address_space(3))) uint32_t*)l, 16, 0, 0);
}

// ---------------------------------------------------------------------------
// Wide split-bf16 MFMA GEMM for layers 1/2: C[M,256] = (Ah+Al)@(Wh+Wl)^T
// BM=64, BN=256 (full width -> A panel read exactly ONCE), BK=32.
// ---------------------------------------------------------------------------
__global__ __launch_bounds__(256) void gemm_wide(
    const ushort* __restrict__ Ah, const ushort* __restrict__ Al,
    const ushort* __restrict__ Bh, const ushort* __restrict__ Bl,
    ushort* __restrict__ Cout, int M, int K) {
  __shared__ ushort AsH[64 * 32];
  __shared__ ushort AsL[64 * 32];
  __shared__ ushort BsH[256 * 32];
  __shared__ ushort BsL[256 * 32];

  const int t = threadIdx.x;
  const int w = t >> 6, ln = t & 63;
  const int row0 = blockIdx.x * 64;
  const int wr = (w >> 1) * 32, wc = (w & 1) * 128;

  f32x4 acc[2][8] = {};

  const int nkt = K >> 5;
  for (int kt = 0; kt < nkt; ++kt) {
    const int k0 = kt << 5;
    {
      int rloc = w * 16 + (ln >> 2);
      int sl = ln & 3;
      int sg = sl ^ ((rloc ^ (rloc >> 2)) & 3);
      int grow = row0 + rloc; grow = grow < M ? grow : M - 1;
      size_t go = (size_t)grow * K + k0 + sg * 8;
      gload_lds16(Ah + go, AsH + w * 512);
      gload_lds16(Al + go, AsL + w * 512);
    }
    #pragma unroll
    for (int i = 0; i < 4; ++i) {
      int rloc = w * 64 + i * 16 + (ln >> 2);
      int sl = ln & 3;
      int sg = sl ^ ((rloc ^ (rloc >> 2)) & 3);
      size_t go = (size_t)rloc * K + k0 + sg * 8;
      gload_lds16(Bh + go, BsH + (w * 64 + i * 16) * 32);
      gload_lds16(Bl + go, BsL + (w * 64 + i * 16) * 32);
    }
    __syncthreads();

    short8 ah[2], al[2], bh[8], bl[8];
    #pragma unroll
    for (int i = 0; i < 2; ++i) {
      int row = wr + i * 16 + (ln & 15);
      int slot = (ln >> 4) ^ ((row ^ (row >> 2)) & 3);
      int off = row * 32 + slot * 8;
      ah[i] = *(const short8*)(AsH + off);
      al[i] = *(const short8*)(AsL + off);
    }
    #pragma unroll
    for (int j = 0; j < 8; ++j) {
      int col = wc + j * 16 + (ln & 15);
      int slot = (ln >> 4) ^ ((col ^ (col >> 2)) & 3);
      int off = col * 32 + slot * 8;
      bh[j] = *(const short8*)(BsH + off);
      bl[j] = *(const short8*)(BsL + off);
    }
    #pragma unroll
    for (int i = 0; i < 2; ++i)
      #pragma unroll
      for (int j = 0; j < 8; ++j) {
        acc[i][j] = __builtin_amdgcn_mfma_f32_16x16x32_bf16(ah[i], bh[j], acc[i][j], 0, 0, 0);
        acc[i][j] = __builtin_amdgcn_mfma_f32_16x16x32_bf16(al[i], bh[j], acc[i][j], 0, 0, 0);
        acc[i][j] = __builtin_amdgcn_mfma_f32_16x16x32_bf16(ah[i], bl[j], acc[i][j], 0, 0, 0);
      }
    __syncthreads();
  }

  #pragma unroll
  for (int i = 0; i < 2; ++i)
    #pragma unroll
    for (int j = 0; j < 8; ++j)
      #pragma unroll
      for (int r = 0; r < 4; ++r) {
        int grow = row0 + wr + i * 16 + (ln >> 4) * 4 + r;
        int gcol = wc + j * 16 + (ln & 15);
        if (grow < M) Cout[(size_t)grow * 256 + gcol] = f2bf(acc[i][j][r]);
      }
}

// ---------------------------------------------------------------------------
// Narrow split-bf16 MFMA GEMM (layer 3, Ncols=64): BM=128, BN=64, BK=64.
// bf16 output (h3 gathered as bf16 by aggr_f3).
// ---------------------------------------------------------------------------
__global__ __launch_bounds__(256) void gemm_mfma3(
    const ushort* __restrict__ Ah, const ushort* __restrict__ Al,
    const ushort* __restrict__ Bh, const ushort* __restrict__ Bl,
    ushort* __restrict__ Cout, int M, int K, int Ncols) {
  __shared__ ushort AsH[128 * 64];
  __shared__ ushort AsL[128 * 64];
  __shared__ ushort BsH[64 * 64];
  __shared__ ushort BsL[64 * 64];

  const int t = threadIdx.x;
  const int w = t >> 6, ln = t & 63;
  const int row0 = blockIdx.y * 128;
  const int col0 = blockIdx.x * 64;
  const int wr = (w >> 1) * 64, wc = (w & 1) * 32;

  f32x4 acc[4][2] = {};

  const int nkt = K >> 6;
  for (int kt = 0; kt < nkt; ++kt) {
    const int k0 = kt << 6;
    #pragma unroll
    for (int i = 0; i < 4; ++i) {
      int row8 = w * 4 + i;
      int rloc = row8 * 8 + (ln >> 3);
      int sslot = (ln & 7) ^ (rloc & 7);
      int grow = row0 + rloc; grow = grow < M ? grow : M - 1;
      size_t go = (size_t)grow * K + k0 + sslot * 8;
      gload_lds16(Ah + go, AsH + row8 * 512);
      gload_lds16(Al + go, AsL + row8 * 512);
    }
    #pragma unroll
    for (int i = 0; i < 2; ++i) {
      int row8 = w * 2 + i;
      int rloc = row8 * 8 + (ln >> 3);
      int sslot = (ln & 7) ^ (rloc & 7);
      size_t go = (size_t)(col0 + rloc) * K + k0 + sslot * 8;
      gload_lds16(Bh + go, BsH + row8 * 512);
      gload_lds16(Bl + go, BsL + row8 * 512);
    }
    __syncthreads();

    #pragma unroll
    for (int ks = 0; ks < 2; ++ks) {
      short8 ah[4], al[4], bh[2], bl[2];
      #pragma unroll
      for (int i = 0; i < 4; ++i) {
        int row = wr + i * 16 + (ln & 15);
        int slot = (ks * 4 + (ln >> 4)) ^ (row & 7);
        int off = row * 64 + slot * 8;
        ah[i] = *(const short8*)(AsH + off);
        al[i] = *(const short8*)(AsL + off);
      }
      #pragma unroll
      for (int j = 0; j < 2; ++j) {
        int col = wc + j * 16 + (ln & 15);
        int slot = (ks * 4 + (ln >> 4)) ^ (col & 7);
        int off = col * 64 + slot * 8;
        bh[j] = *(const short8*)(BsH + off);
        bl[j] = *(const short8*)(BsL + off);
      }
      #pragma unroll
      for (int i = 0; i < 4; ++i)
        #pragma unroll
        for (int j = 0; j < 2; ++j) {
          acc[i][j] = __builtin_amdgcn_mfma_f32_16x16x32_bf16(ah[i], bh[j], acc[i][j], 0, 0, 0);
          acc[i][j] = __builtin_amdgcn_mfma_f32_16x16x32_bf16(al[i], bh[j], acc[i][j], 0, 0, 0);
          acc[i][j] = __builtin_amdgcn_mfma_f32_16x16x32_bf16(ah[i], bl[j], acc[i][j], 0, 0, 0);
        }
    }
    __syncthreads();
  }

  #pragma unroll
  for (int i = 0; i < 4; ++i)
    #pragma unroll
    for (int j = 0; j < 2; ++j)
      #pragma unroll
      for (int r = 0; r < 4; ++r) {
        int grow = row0 + wr + i * 16 + (ln >> 4) * 4 + r;
        int gcol = col0 + wc + j * 16 + (ln & 15);
        if (grow < M) Cout[(size_t)grow * Ncols + gcol] = f2bf(acc[i][j][r]);
      }
}

// ---------------------------------------------------------------------------
// fp32 -> bf16 hi/lo split (elementwise, float4-vectorized)
// ---------------------------------------------------------------------------
__global__ void cvt_split(const float* __restrict__ in, ushort* __restrict__ hi,
                          ushort* __restrict__ lo, int n4) {
  int idx = blockIdx.x * blockDim.x + threadIdx.x;
  if (idx >= n4) return;
  float4 v = ((const float4*)in)[idx];
  ushort4 h, l;
  h.x = f2bf(v.x); l.x = f2bf(v.x - bf2f(h.x));
  h.y = f2bf(v.y); l.y = f2bf(v.y - bf2f(h.y));
  h.z = f2bf(v.z); l.z = f2bf(v.z - bf2f(h.z));
  h.w = f2bf(v.w); l.w = f2bf(v.w - bf2f(h.w));
  ((ushort4*)hi)[idx] = h;
  ((ushort4*)lo)[idx] = l;
}

// W [K][N] fp32 -> Wt [N][K] bf16 hi/lo (tiny)
__global__ void cvt_w(const float* __restrict__ W, ushort* __restrict__ th,
                      ushort* __restrict__ tl, int K, int N) {
  int idx = blockIdx.x * blockDim.x + threadIdx.x;
  if (idx >= K * N) return;
  int k = idx / N, c = idx - k * N;
  float f = W[idx];
  ushort h = f2bf(f);
  th[(size_t)c * K + k] = h;
  tl[(size_t)c * K + k] = f2bf(f - bf2f(h));
}

// ---------------------------------------------------------------------------
// alpha coefficients from bf16 h (layers 1/2: H=8, C=32)
// ---------------------------------------------------------------------------
__global__ void alpha_bf(const ushort* __restrict__ h, const float* __restrict__ a_src,
                         const float* __restrict__ a_dst, float* __restrict__ as_out,
                         float* __restrict__ ad_out, int n) {
  int idx = blockIdx.x * blockDim.x + threadIdx.x;
  if (idx >= n * 8) return;
  int node = idx >> 3, hd = idx & 7;
  const uint32_t* hp = (const uint32_t*)(h + (size_t)node * 256 + hd * 32);
  float s1 = 0.f, s2 = 0.f;
  #pragma unroll
  for (int q = 0; q < 16; ++q) {
    uint32_t u = hp[q];
    float f0 = bflo(u), f1 = bfhi(u);
    s1 += f0 * a_src[hd * 32 + 2 * q] + f1 * a_src[hd * 32 + 2 * q + 1];
    s2 += f0 * a_dst[hd * 32 + 2 * q] + f1 * a_dst[hd * 32 + 2 * q + 1];
  }
  as_out[idx] = s1;
  ad_out[idx] = s2;
}

// alpha for layer 3 (H=1, C=64, bf16 h)
__global__ void alpha_f3(const ushort* __restrict__ h, const float* __restrict__ a_src,
                         const float* __restrict__ a_dst, float* __restrict__ as_out,
                         float* __restrict__ ad_out, int n) {
  int idx = blockIdx.x * blockDim.x + threadIdx.x;
  if (idx >= n) return;
  const uint32_t* hp = (const uint32_t*)(h + (size_t)idx * 64);
  float s1 = 0.f, s2 = 0.f;
  #pragma unroll
  for (int q = 0; q < 32; ++q) {
    uint32_t u = hp[q];
    float f0 = bflo(u), f1 = bfhi(u);
    s1 += f0 * a_src[2 * q] + f1 * a_src[2 * q + 1];
    s2 += f0 * a_dst[2 * q] + f1 * a_dst[2 * q + 1];
  }
  as_out[idx] = s1;
  ad_out[idx] = s2;
}

// ---------------------------------------------------------------------------
// CSR build
// ---------------------------------------------------------------------------
__global__ void deg_kernel(const int* __restrict__ dst, int* __restrict__ deg, int E) {
  int e = blockIdx.x * blockDim.x + threadIdx.x;
  if (e < E) atomicAdd(&deg[dst[e]], 1);
}

__global__ __launch_bounds__(256) void scan_partial(const int* __restrict__ deg,
                                                    int* __restrict__ rowptr,
                                                    int* __restrict__ blocksum, int n) {
  __shared__ int sdata[256];
  int t = threadIdx.x;
  int base = blockIdx.x * 1024 + t * 4;
  int v[4], s = 0;
  #pragma unroll
  for (int i = 0; i < 4; ++i) {
    v[i] = (base + i < n) ? deg[base + i] : 0;
    s += v[i];
  }
  sdata[t] = s;
  __syncthreads();
  for (int off = 1; off < 256; off <<= 1) {
    int x = (t >= off) ? sdata[t - off] : 0;
    __syncthreads();
    sdata[t] += x;
    __syncthreads();
  }
  int run = sdata[t] - s;
  #pragma unroll
  for (int i = 0; i < 4; ++i) {
    if (base + i < n) rowptr[base + i] = run;
    run += v[i];
  }
  if (t == 255) blocksum[blockIdx.x] = sdata[255];
}

__global__ __launch_bounds__(256) void scan_blocksums(int* __restrict__ blocksum, int nb) {
  __shared__ int sdata[256];
  int t = threadIdx.x;
  int v = (t < nb) ? blocksum[t] : 0;
  sdata[t] = v;
  __syncthreads();
  for (int off = 1; off < 256; off <<= 1) {
    int x = (t >= off) ? sdata[t - off] : 0;
    __syncthreads();
    sdata[t] += x;
    __syncthreads();
  }
  if (t < nb) blocksum[t] = sdata[t] - v;
}

__global__ void scan_add(int* __restrict__ rowptr, const int* __restrict__ blocksum,
                         int n, int E) {
  int idx = blockIdx.x * blockDim.x + threadIdx.x;
  if (idx < n) rowptr[idx] += blocksum[idx >> 10];
  if (idx == n) rowptr[n] = E;
}

__global__ void scatter_kernel(const int* __restrict__ src, const int* __restrict__ dst,
                               const int* __restrict__ rowptr, int* __restrict__ cursor,
                               int* __restrict__ col_src, int E) {
  int e = blockIdx.x * blockDim.x + threadIdx.x;
  if (e >= E) return;
  int d = dst[e];
  int pos = rowptr[d] + atomicAdd(&cursor[d], 1);
  col_src[pos] = src[e];
}

// ---------------------------------------------------------------------------
// Fused per-dst softmax + aggregate. 2 dst per wave (half-wave each, 32
// lanes x 8ch = 256 ch, uint4 16B gathers). 2-edge unroll per half.
// bf16 h gather, split bf16 hi/lo output with ELU.
// ---------------------------------------------------------------------------
__global__ __launch_bounds__(256) void aggr_bf(
    const int* __restrict__ rowptr, const int* __restrict__ col_src,
    const ushort* __restrict__ h, const float* __restrict__ as_,
    const float* __restrict__ ad_, const float* __restrict__ bias,
    ushort* __restrict__ oh, ushort* __restrict__ ol, int n) {
  int wid = (blockIdx.x * 256 + threadIdx.x) >> 6;
  int d = wid * 2 + ((threadIdx.x >> 5) & 1);
  if (d >= n) return;
  int l = threadIdx.x & 31;
  int c0 = l * 8;
  int hd = l >> 2;  // c0 / 32
  float ad_d = ad_[d * 8 + hd];
  float a0 = 0.f, a1 = 0.f, a2 = 0.f, a3 = 0.f;
  float a4 = 0.f, a5 = 0.f, a6 = 0.f, a7 = 0.f, denom = 0.f;
  int beg = rowptr[d], end = rowptr[d + 1];
  int i = beg;
  for (; i + 2 <= end; i += 2) {
    int s0 = col_src[i], s1 = col_src[i + 1];
    float l0 = as_[s0 * 8 + hd] + ad_d;
    float l1 = as_[s1 * 8 + hd] + ad_d;
    uint4 v0 = *(const uint4*)(h + (size_t)s0 * 256 + c0);
    uint4 v1 = *(const uint4*)(h + (size_t)s1 * 256 + c0);
    l0 = (l0 > 0.f) ? l0 : 0.2f * l0;
    l1 = (l1 > 0.f) ? l1 : 0.2f * l1;
    float e0 = __expf(l0), e1 = __expf(l1);
    denom += e0 + e1;
    a0 += e0 * bflo(v0.x) + e1 * bflo(v1.x);
    a1 += e0 * bfhi(v0.x) + e1 * bfhi(v1.x);
    a2 += e0 * bflo(v0.y) + e1 * bflo(v1.y);
    a3 += e0 * bfhi(v0.y) + e1 * bfhi(v1.y);
    a4 += e0 * bflo(v0.z) + e1 * bflo(v1.z);
    a5 += e0 * bfhi(v0.z) + e1 * bfhi(v1.z);
    a6 += e0 * bflo(v0.w) + e1 * bflo(v1.w);
    a7 += e0 * bfhi(v0.w) + e1 * bfhi(v1.w);
  }
  if (i < end) {
    int s = col_src[i];
    float lg = as_[s * 8 + hd] + ad_d;
    lg = (lg > 0.f) ? lg : 0.2f * lg;
    float ev = __expf(lg);
    denom += ev;
    uint4 v = *(const uint4*)(h + (size_t)s * 256 + c0);
    a0 += ev * bflo(v.x);
    a1 += ev * bfhi(v.x);
    a2 += ev * bflo(v.y);
    a3 += ev * bfhi(v.y);
    a4 += ev * bflo(v.z);
    a5 += ev * bfhi(v.z);
    a6 += ev * bflo(v.w);
    a7 += ev * bfhi(v.w);
  }
  float inv = 1.f / (denom + 1e-16f);
  float vv[8] = {a0, a1, a2, a3, a4, a5, a6, a7};
  ushort8v hh, ll;
  #pragma unroll
  for (int j = 0; j < 8; ++j) {
    float v = vv[j] * inv + bias[c0 + j];
    v = (v > 0.f) ? v : expm1f(v);
    ushort hb = f2bf(v);
    hh[j] = hb;
    ll[j] = f2bf(v - bf2f(hb));
  }
  *(ushort8v*)(oh + (size_t)d * 256 + c0) = hh;
  *(ushort8v*)(ol + (size_t)d * 256 + c0) = ll;
}

// Layer 3: bf16 h gather, 4 dst per wave (16 lanes x 4ch = 64 ch, uint2 8B
// gathers), fp32 out, no ELU.
__global__ __launch_bounds__(256) void aggr_f3(
    const int* __restrict__ rowptr, const int* __restrict__ col_src,
    const ushort* __restrict__ h, const float* __restrict__ as_,
    const float* __restrict__ ad_, const float* __restrict__ bias,
    float* __restrict__ outp, int n) {
  int wid = (blockIdx.x * 256 + threadIdx.x) >> 6;
  int d = wid * 4 + ((threadIdx.x >> 4) & 3);
  if (d >= n) return;
  int l = threadIdx.x & 15;
  int c0 = l * 4;
  float ad_d = ad_[d];
  float a0 = 0.f, a1 = 0.f, a2 = 0.f, a3 = 0.f, denom = 0.f;
  int beg = rowptr[d], end = rowptr[d + 1];
  int i = beg;
  for (; i + 2 <= end; i += 2) {
    int s0 = col_src[i], s1 = col_src[i + 1];
    float l0 = as_[s0] + ad_d;
    float l1 = as_[s1] + ad_d;
    uint2 v0 = *(const uint2*)(h + (size_t)s0 * 64 + c0);
    uint2 v1 = *(const uint2*)(h + (size_t)s1 * 64 + c0);
    l0 = (l0 > 0.f) ? l0 : 0.2f * l0;
    l1 = (l1 > 0.f) ? l1 : 0.2f * l1;
    float e0 = __expf(l0), e1 = __expf(l1);
    denom += e0 + e1;
    a0 += e0 * bflo(v0.x) + e1 * bflo(v1.x);
    a1 += e0 * bfhi(v0.x) + e1 * bfhi(v1.x);
    a2 += e0 * bflo(v0.y) + e1 * bflo(v1.y);
    a3 += e0 * bfhi(v0.y) + e1 * bfhi(v1.y);
  }
  if (i < end) {
    int s = col_src[i];
    float lg = as_[s] + ad_d;
    lg = (lg > 0.f) ? lg : 0.2f * lg;
    float ev = __expf(lg);
    denom += ev;
    uint2 v = *(const uint2*)(h + (size_t)s * 64 + c0);
    a0 += ev * bflo(v.x);
    a1 += ev * bfhi(v.x);
    a2 += ev * bflo(v.y);
    a3 += ev * bfhi(v.y);
  }
  float inv = 1.f / (denom + 1e-16f);
  float4 r;
  r.x = a0 * inv + bias[c0 + 0];
  r.y = a1 * inv + bias[c0 + 1];
  r.z = a2 * inv + bias[c0 + 2];
  r.w = a3 * inv + bias[c0 + 3];
  *(float4*)(outp + (size_t)d * 64 + c0) = r;
}

// ---------------------------------------------------------------------------

extern "C" void kernel_launch(void* const* d_in, const int* in_sizes, int n_in,
                              void* d_out, int out_size, void* d_ws, size_t ws_size,
                              hipStream_t stream) {
  const float* x   = (const float*)d_in[0];
  const int*   ei  = (const int*)d_in[1];
  const float* W1  = (const float*)d_in[2];
  const float* aS1 = (const float*)d_in[3];
  const float* aD1 = (const float*)d_in[4];
  const float* b1  = (const float*)d_in[5];
  const float* W2  = (const float*)d_in[6];
  const float* aS2 = (const float*)d_in[7];
  const float* aD2 = (const float*)d_in[8];
  const float* b2  = (const float*)d_in[9];
  const float* W3  = (const float*)d_in[10];
  const float* aS3 = (const float*)d_in[11];
  const float* aD3 = (const float*)d_in[12];
  const float* b3  = (const float*)d_in[13];

  const int* srcp = ei;
  const int* dstp = ei + NEDGES;

  // ---- arena (~110 MB) ----
  char* base = (char*)d_ws;
  size_t o = 0;
  ushort* hbf  = (ushort*)(base + o); o += 25600000;   // h: N*256 bf16 (or N*64 bf16 L3)
  ushort* fh   = (ushort*)(base + o); o += 25600000;   // feat hi
  ushort* fl   = (ushort*)(base + o); o += 25600000;   // feat lo
  ushort* f1h  = (ushort*)(base + o); o += 12800000;   // layer-1 input hi
  ushort* f1l  = (ushort*)(base + o); o += 12800000;   // layer-1 input lo
  float*  as_  = (float*)(base + o);  o += 1600000;
  float*  ad_  = (float*)(base + o);  o += 1600000;
  ushort* w1h  = (ushort*)(base + o); o += 65536;
  ushort* w1l  = (ushort*)(base + o); o += 65536;
  ushort* w2h  = (ushort*)(base + o); o += 131072;
  ushort* w2l  = (ushort*)(base + o); o += 131072;
  ushort* w3h  = (ushort*)(base + o); o += 32768;
  ushort* w3l  = (ushort*)(base + o); o += 32768;
  int* rowptr  = (int*)(base + o);    o += 200016;
  int* cursor  = (int*)(base + o);    o += 200000;
  int* colsrc  = (int*)(base + o);    o += 3200000;
  int* bsum    = (int*)(base + o);    o += 1024;
  float* outp  = (float*)d_out;

  // ---- CSR build (edge structure shared by all 3 layers) ----
  hipMemsetAsync(cursor, 0, NNODES * sizeof(int), stream);
  deg_kernel<<<(NEDGES + 255) / 256, 256, 0, stream>>>(dstp, cursor, NEDGES);
  int nb = (NNODES + 1023) / 1024;  // 49
  scan_partial<<<nb, 256, 0, stream>>>(cursor, rowptr, bsum, NNODES);
  scan_blocksums<<<1, 256, 0, stream>>>(bsum, nb);
  scan_add<<<(NNODES + 256) / 256, 256, 0, stream>>>(rowptr, bsum, NNODES, NEDGES);
  hipMemsetAsync(cursor, 0, NNODES * sizeof(int), stream);
  scatter_kernel<<<(NEDGES + 255) / 256, 256, 0, stream>>>(srcp, dstp, rowptr, cursor,
                                                           colsrc, NEDGES);

  // ---- weight / input conversions ----
  cvt_split<<<(NNODES * 128 / 4 + 255) / 256, 256, 0, stream>>>(x, f1h, f1l,
                                                                NNODES * 128 / 4);
  cvt_w<<<(128 * 256 + 255) / 256, 256, 0, stream>>>(W1, w1h, w1l, 128, 256);
  cvt_w<<<(256 * 256 + 255) / 256, 256, 0, stream>>>(W2, w2h, w2l, 256, 256);
  cvt_w<<<(256 * 64 + 255) / 256, 256, 0, stream>>>(W3, w3h, w3l, 256, 64);

  const int ga2 = (NNODES + 7) / 8;    // aggr_bf: 8 dst per 256-thr block
  const int ga4 = (NNODES + 15) / 16;  // aggr_f3: 16 dst per block
  const int gw  = (NNODES + 63) / 64;  // gemm_wide grid
  // ---- layer 1: x -> fh/fl ----
  gemm_wide<<<gw, 256, 0, stream>>>(f1h, f1l, w1h, w1l, hbf, NNODES, 128);
  alpha_bf<<<(NNODES * 8 + 255) / 256, 256, 0, stream>>>(hbf, aS1, aD1, as_, ad_, NNODES);
  aggr_bf<<<ga2, 256, 0, stream>>>(rowptr, colsrc, hbf, as_, ad_, b1, fh, fl, NNODES);
  // ---- layer 2: fh/fl -> fh/fl ----
  gemm_wide<<<gw, 256, 0, stream>>>(fh, fl, w2h, w2l, hbf, NNODES, 256);
  alpha_bf<<<(NNODES * 8 + 255) / 256, 256, 0, stream>>>(hbf, aS2, aD2, as_, ad_, NNODES);
  aggr_bf<<<ga2, 256, 0, stream>>>(rowptr, colsrc, hbf, as_, ad_, b2, fh, fl, NNODES);
  // ---- layer 3: fh/fl -> d_out (bf16 h gather, fp32 accum/out) ----
  gemm_mfma3<<<dim3(1, (NNODES + 127) / 128), 256, 0, stream>>>(
      fh, fl, w3h, w3l, hbf, NNODES, 256, 64);
  alpha_f3<<<(NNODES + 255) / 256, 256, 0, stream>>>(hbf, aS3, aD3, as_, ad_, NNODES);
  aggr_f3<<<ga4, 256, 0, stream>>>(rowptr, colsrc, hbf, as_, ad_, b3, outp, NNODES);
}

// Round 6
// 379.785 us; speedup vs baseline: 15.9122x; 1.0773x over previous
//
#include <hip/hip_runtime.h>
#include <hip/hip_bf16.h>
#include <stdint.h>

#define NNODES 50000
#define NEDGES 800000

typedef float f32x4 __attribute__((ext_vector_type(4)));
typedef short short8 __attribute__((ext_vector_type(8)));

__device__ __forceinline__ ushort f2bf(float f) {
  uint32_t u = __float_as_uint(f);
  u += 0x7fff + ((u >> 16) & 1);   // RNE
  return (ushort)(u >> 16);
}
__device__ __forceinline__ float bf2f(ushort h) {
  return __uint_as_float(((uint32_t)h) << 16);
}
__device__ __forceinline__ float bflo(uint32_t u) { return __uint_as_float(u << 16); }
__device__ __forceinline__ float bfhi(uint32_t u) { return __uint_as_float(u & 0xffff0000u); }

__device__ __forceinline__ void gload_lds16(const void* g, void* l) {
  __builtin_amdgcn_global_load_lds(
      (const __attribute__((address_space(1))) uint32_t*)g,
      (__attribute__((address_space(3))) uint32_t*)l, 16, 0, 0);
}

// ---------------------------------------------------------------------------
// Wide split-bf16 MFMA GEMM for layers 1/2: C[M,256] = (Ah+Al)@(Wh+Wl)^T
// BM=64, BN=256 (full width -> A panel read once), BK=32. bf16 out.
// FUSED alpha epilogue: as/ad[node,head] = sum_c h(fp32 acc)*a_{src,dst}[head,c]
// via 16-lane shfl reduce; heads are disjoint across col-waves -> no LDS.
// ---------------------------------------------------------------------------
__global__ __launch_bounds__(256) void gemm_wide(
    const ushort* __restrict__ Ah, const ushort* __restrict__ Al,
    const ushort* __restrict__ Bh, const ushort* __restrict__ Bl,
    const float* __restrict__ a_src, const float* __restrict__ a_dst,
    float* __restrict__ as_out, float* __restrict__ ad_out,
    ushort* __restrict__ Cout, int M, int K) {
  __shared__ ushort AsH[64 * 32];
  __shared__ ushort AsL[64 * 32];
  __shared__ ushort BsH[256 * 32];
  __shared__ ushort BsL[256 * 32];

  const int t = threadIdx.x;
  const int w = t >> 6, ln = t & 63;
  const int row0 = blockIdx.x * 64;
  const int wr = (w >> 1) * 32, wc = (w & 1) * 128;

  f32x4 acc[2][8] = {};

  const int nkt = K >> 5;
  for (int kt = 0; kt < nkt; ++kt) {
    const int k0 = kt << 5;
    {
      int rloc = w * 16 + (ln >> 2);
      int sl = ln & 3;
      int sg = sl ^ ((rloc ^ (rloc >> 2)) & 3);
      int grow = row0 + rloc; grow = grow < M ? grow : M - 1;
      size_t go = (size_t)grow * K + k0 + sg * 8;
      gload_lds16(Ah + go, AsH + w * 512);
      gload_lds16(Al + go, AsL + w * 512);
    }
    #pragma unroll
    for (int i = 0; i < 4; ++i) {
      int rloc = w * 64 + i * 16 + (ln >> 2);
      int sl = ln & 3;
      int sg = sl ^ ((rloc ^ (rloc >> 2)) & 3);
      size_t go = (size_t)rloc * K + k0 + sg * 8;
      gload_lds16(Bh + go, BsH + (w * 64 + i * 16) * 32);
      gload_lds16(Bl + go, BsL + (w * 64 + i * 16) * 32);
    }
    __syncthreads();

    short8 ah[2], al[2], bh[8], bl[8];
    #pragma unroll
    for (int i = 0; i < 2; ++i) {
      int row = wr + i * 16 + (ln & 15);
      int slot = (ln >> 4) ^ ((row ^ (row >> 2)) & 3);
      int off = row * 32 + slot * 8;
      ah[i] = *(const short8*)(AsH + off);
      al[i] = *(const short8*)(AsL + off);
    }
    #pragma unroll
    for (int j = 0; j < 8; ++j) {
      int col = wc + j * 16 + (ln & 15);
      int slot = (ln >> 4) ^ ((col ^ (col >> 2)) & 3);
      int off = col * 32 + slot * 8;
      bh[j] = *(const short8*)(BsH + off);
      bl[j] = *(const short8*)(BsL + off);
    }
    #pragma unroll
    for (int i = 0; i < 2; ++i)
      #pragma unroll
      for (int j = 0; j < 8; ++j) {
        acc[i][j] = __builtin_amdgcn_mfma_f32_16x16x32_bf16(ah[i], bh[j], acc[i][j], 0, 0, 0);
        acc[i][j] = __builtin_amdgcn_mfma_f32_16x16x32_bf16(al[i], bh[j], acc[i][j], 0, 0, 0);
        acc[i][j] = __builtin_amdgcn_mfma_f32_16x16x32_bf16(ah[i], bl[j], acc[i][j], 0, 0, 0);
      }
    __syncthreads();
  }

  const int lx = ln & 15, g = ln >> 4;

  // ---- C write (C/D layout: col=lane&15, row=(lane>>4)*4+reg) ----
  #pragma unroll
  for (int i = 0; i < 2; ++i)
    #pragma unroll
    for (int j = 0; j < 8; ++j)
      #pragma unroll
      for (int r = 0; r < 4; ++r) {
        int grow = row0 + wr + i * 16 + g * 4 + r;
        int gcol = wc + j * 16 + lx;
        if (grow < M) Cout[(size_t)grow * 256 + gcol] = f2bf(acc[i][j][r]);
      }

  // ---- fused alpha epilogue ----
  const int hbase = wc >> 5;  // heads 0-3 (wc=0) or 4-7 (wc=128)
  float avs[8], avd[8];
  #pragma unroll
  for (int j = 0; j < 8; ++j) {
    avs[j] = a_src[wc + j * 16 + lx];
    avd[j] = a_dst[wc + j * 16 + lx];
  }
  #pragma unroll
  for (int i = 0; i < 2; ++i)
    #pragma unroll
    for (int r = 0; r < 4; ++r) {
      float ps[4] = {0.f, 0.f, 0.f, 0.f}, pd[4] = {0.f, 0.f, 0.f, 0.f};
      #pragma unroll
      for (int j = 0; j < 8; ++j) {
        float v = acc[i][j][r];
        ps[j >> 1] += v * avs[j];
        pd[j >> 1] += v * avd[j];
      }
      #pragma unroll
      for (int m = 1; m < 16; m <<= 1)
        #pragma unroll
        for (int q = 0; q < 4; ++q) {
          ps[q] += __shfl_xor(ps[q], m);
          pd[q] += __shfl_xor(pd[q], m);
        }
      if (lx == 0) {
        int grow = row0 + wr + i * 16 + g * 4 + r;
        if (grow < M) {
          #pragma unroll
          for (int q = 0; q < 4; ++q) {
            as_out[grow * 8 + hbase + q] = ps[q];
            ad_out[grow * 8 + hbase + q] = pd[q];
          }
        }
      }
    }
}

// ---------------------------------------------------------------------------
// Narrow split-bf16 MFMA GEMM (layer 3, Ncols=64): BM=128, BN=64, BK=64.
// bf16 h out. FUSED alpha (H=1, C=64): 16-lane shfl reduce + LDS combine
// across the 2 col-waves.
// ---------------------------------------------------------------------------
__global__ __launch_bounds__(256) void gemm_mfma3(
    const ushort* __restrict__ Ah, const ushort* __restrict__ Al,
    const ushort* __restrict__ Bh, const ushort* __restrict__ Bl,
    const float* __restrict__ a_src, const float* __restrict__ a_dst,
    float* __restrict__ as_out, float* __restrict__ ad_out,
    ushort* __restrict__ Cout, int M, int K, int Ncols) {
  __shared__ ushort AsH[128 * 64];
  __shared__ ushort AsL[128 * 64];
  __shared__ ushort BsH[64 * 64];
  __shared__ ushort BsL[64 * 64];
  __shared__ float redS[2][128], redD[2][128];

  const int t = threadIdx.x;
  const int w = t >> 6, ln = t & 63;
  const int row0 = blockIdx.y * 128;
  const int col0 = blockIdx.x * 64;
  const int wr = (w >> 1) * 64, wc = (w & 1) * 32;

  f32x4 acc[4][2] = {};

  const int nkt = K >> 6;
  for (int kt = 0; kt < nkt; ++kt) {
    const int k0 = kt << 6;
    #pragma unroll
    for (int i = 0; i < 4; ++i) {
      int row8 = w * 4 + i;
      int rloc = row8 * 8 + (ln >> 3);
      int sslot = (ln & 7) ^ (rloc & 7);
      int grow = row0 + rloc; grow = grow < M ? grow : M - 1;
      size_t go = (size_t)grow * K + k0 + sslot * 8;
      gload_lds16(Ah + go, AsH + row8 * 512);
      gload_lds16(Al + go, AsL + row8 * 512);
    }
    #pragma unroll
    for (int i = 0; i < 2; ++i) {
      int row8 = w * 2 + i;
      int rloc = row8 * 8 + (ln >> 3);
      int sslot = (ln & 7) ^ (rloc & 7);
      size_t go = (size_t)(col0 + rloc) * K + k0 + sslot * 8;
      gload_lds16(Bh + go, BsH + row8 * 512);
      gload_lds16(Bl + go, BsL + row8 * 512);
    }
    __syncthreads();

    #pragma unroll
    for (int ks = 0; ks < 2; ++ks) {
      short8 ah[4], al[4], bh[2], bl[2];
      #pragma unroll
      for (int i = 0; i < 4; ++i) {
        int row = wr + i * 16 + (ln & 15);
        int slot = (ks * 4 + (ln >> 4)) ^ (row & 7);
        int off = row * 64 + slot * 8;
        ah[i] = *(const short8*)(AsH + off);
        al[i] = *(const short8*)(AsL + off);
      }
      #pragma unroll
      for (int j = 0; j < 2; ++j) {
        int col = wc + j * 16 + (ln & 15);
        int slot = (ks * 4 + (ln >> 4)) ^ (col & 7);
        int off = col * 64 + slot * 8;
        bh[j] = *(const short8*)(BsH + off);
        bl[j] = *(const short8*)(BsL + off);
      }
      #pragma unroll
      for (int i = 0; i < 4; ++i)
        #pragma unroll
        for (int j = 0; j < 2; ++j) {
          acc[i][j] = __builtin_amdgcn_mfma_f32_16x16x32_bf16(ah[i], bh[j], acc[i][j], 0, 0, 0);
          acc[i][j] = __builtin_amdgcn_mfma_f32_16x16x32_bf16(al[i], bh[j], acc[i][j], 0, 0, 0);
          acc[i][j] = __builtin_amdgcn_mfma_f32_16x16x32_bf16(ah[i], bl[j], acc[i][j], 0, 0, 0);
        }
    }
    __syncthreads();
  }

  const int lx = ln & 15, g = ln >> 4;

  #pragma unroll
  for (int i = 0; i < 4; ++i)
    #pragma unroll
    for (int j = 0; j < 2; ++j)
      #pragma unroll
      for (int r = 0; r < 4; ++r) {
        int grow = row0 + wr + i * 16 + g * 4 + r;
        int gcol = col0 + wc + j * 16 + lx;
        if (grow < M) Cout[(size_t)grow * Ncols + gcol] = f2bf(acc[i][j][r]);
      }

  // ---- fused alpha (single head over 64 cols) ----
  float avs[2], avd[2];
  #pragma unroll
  for (int j = 0; j < 2; ++j) {
    avs[j] = a_src[wc + j * 16 + lx];
    avd[j] = a_dst[wc + j * 16 + lx];
  }
  #pragma unroll
  for (int i = 0; i < 4; ++i)
    #pragma unroll
    for (int r = 0; r < 4; ++r) {
      float ps = 0.f, pd = 0.f;
      #pragma unroll
      for (int j = 0; j < 2; ++j) {
        float v = acc[i][j][r];
        ps += v * avs[j];
        pd += v * avd[j];
      }
      #pragma unroll
      for (int m = 1; m < 16; m <<= 1) {
        ps += __shfl_xor(ps, m);
        pd += __shfl_xor(pd, m);
      }
      if (lx == 0) {
        int lrow = wr + i * 16 + g * 4 + r;  // 0..127
        redS[w & 1][lrow] = ps;
        redD[w & 1][lrow] = pd;
      }
    }
  __syncthreads();
  if (t < 128) {
    int grow = row0 + t;
    if (grow < M) {
      as_out[grow] = redS[0][t] + redS[1][t];
      ad_out[grow] = redD[0][t] + redD[1][t];
    }
  }
}

// ---------------------------------------------------------------------------
// fp32 -> bf16 hi/lo split (elementwise, float4-vectorized)
// ---------------------------------------------------------------------------
__global__ void cvt_split(const float* __restrict__ in, ushort* __restrict__ hi,
                          ushort* __restrict__ lo, int n4) {
  int idx = blockIdx.x * blockDim.x + threadIdx.x;
  if (idx >= n4) return;
  float4 v = ((const float4*)in)[idx];
  ushort4 h, l;
  h.x = f2bf(v.x); l.x = f2bf(v.x - bf2f(h.x));
  h.y = f2bf(v.y); l.y = f2bf(v.y - bf2f(h.y));
  h.z = f2bf(v.z); l.z = f2bf(v.z - bf2f(h.z));
  h.w = f2bf(v.w); l.w = f2bf(v.w - bf2f(h.w));
  ((ushort4*)hi)[idx] = h;
  ((ushort4*)lo)[idx] = l;
}

// W [K][N] fp32 -> Wt [N][K] bf16 hi/lo (tiny)
__global__ void cvt_w(const float* __restrict__ W, ushort* __restrict__ th,
                      ushort* __restrict__ tl, int K, int N) {
  int idx = blockIdx.x * blockDim.x + threadIdx.x;
  if (idx >= K * N) return;
  int k = idx / N, c = idx - k * N;
  float f = W[idx];
  ushort h = f2bf(f);
  th[(size_t)c * K + k] = h;
  tl[(size_t)c * K + k] = f2bf(f - bf2f(h));
}

// ---------------------------------------------------------------------------
// CSR build
// ---------------------------------------------------------------------------
__global__ void deg_kernel(const int* __restrict__ dst, int* __restrict__ deg, int E) {
  int e = blockIdx.x * blockDim.x + threadIdx.x;
  if (e < E) atomicAdd(&deg[dst[e]], 1);
}

__global__ __launch_bounds__(256) void scan_partial(const int* __restrict__ deg,
                                                    int* __restrict__ rowptr,
                                                    int* __restrict__ blocksum, int n) {
  __shared__ int sdata[256];
  int t = threadIdx.x;
  int base = blockIdx.x * 1024 + t * 4;
  int v[4], s = 0;
  #pragma unroll
  for (int i = 0; i < 4; ++i) {
    v[i] = (base + i < n) ? deg[base + i] : 0;
    s += v[i];
  }
  sdata[t] = s;
  __syncthreads();
  for (int off = 1; off < 256; off <<= 1) {
    int x = (t >= off) ? sdata[t - off] : 0;
    __syncthreads();
    sdata[t] += x;
    __syncthreads();
  }
  int run = sdata[t] - s;
  #pragma unroll
  for (int i = 0; i < 4; ++i) {
    if (base + i < n) rowptr[base + i] = run;
    run += v[i];
  }
  if (t == 255) blocksum[blockIdx.x] = sdata[255];
}

__global__ __launch_bounds__(256) void scan_blocksums(int* __restrict__ blocksum, int nb) {
  __shared__ int sdata[256];
  int t = threadIdx.x;
  int v = (t < nb) ? blocksum[t] : 0;
  sdata[t] = v;
  __syncthreads();
  for (int off = 1; off < 256; off <<= 1) {
    int x = (t >= off) ? sdata[t - off] : 0;
    __syncthreads();
    sdata[t] += x;
    __syncthreads();
  }
  if (t < nb) blocksum[t] = sdata[t] - v;
}

// also re-zeroes cursor for the scatter pass (saves a memset dispatch)
__global__ void scan_add(int* __restrict__ rowptr, const int* __restrict__ blocksum,
                         int* __restrict__ cursor, int n, int E) {
  int idx = blockIdx.x * blockDim.x + threadIdx.x;
  if (idx < n) {
    rowptr[idx] += blocksum[idx >> 10];
    cursor[idx] = 0;
  }
  if (idx == n) rowptr[n] = E;
}

__global__ void scatter_kernel(const int* __restrict__ src, const int* __restrict__ dst,
                               const int* __restrict__ rowptr, int* __restrict__ cursor,
                               int* __restrict__ col_src, int E) {
  int e = blockIdx.x * blockDim.x + threadIdx.x;
  if (e >= E) return;
  int d = dst[e];
  int pos = rowptr[d] + atomicAdd(&cursor[d], 1);
  col_src[pos] = src[e];
}

// ---------------------------------------------------------------------------
// Fused per-dst softmax + aggregate, 1 dst/wave, 2-edge unroll (r4 form —
// fastest measured). bf16 h gather, split bf16 hi/lo output with ELU.
// ---------------------------------------------------------------------------
__global__ __launch_bounds__(256) void aggr_bf(
    const int* __restrict__ rowptr, const int* __restrict__ col_src,
    const ushort* __restrict__ h, const float* __restrict__ as_,
    const float* __restrict__ ad_, const float* __restrict__ bias,
    ushort* __restrict__ oh, ushort* __restrict__ ol, int n) {
  int d = blockIdx.x * 4 + (threadIdx.x >> 6);
  if (d >= n) return;
  int lane = threadIdx.x & 63;
  int c0 = lane * 4;
  int hd = lane >> 3;  // c0 / 32
  float ad_d = ad_[d * 8 + hd];
  float a0 = 0.f, a1 = 0.f, a2 = 0.f, a3 = 0.f, denom = 0.f;
  int beg = rowptr[d], end = rowptr[d + 1];
  int i = beg;
  for (; i + 2 <= end; i += 2) {
    int s0 = col_src[i], s1 = col_src[i + 1];
    float l0 = as_[s0 * 8 + hd] + ad_d;
    float l1 = as_[s1 * 8 + hd] + ad_d;
    uint2 v0 = *(const uint2*)(h + (size_t)s0 * 256 + c0);
    uint2 v1 = *(const uint2*)(h + (size_t)s1 * 256 + c0);
    l0 = (l0 > 0.f) ? l0 : 0.2f * l0;
    l1 = (l1 > 0.f) ? l1 : 0.2f * l1;
    float e0 = __expf(l0), e1 = __expf(l1);
    denom += e0 + e1;
    a0 += e0 * bflo(v0.x) + e1 * bflo(v1.x);
    a1 += e0 * bfhi(v0.x) + e1 * bfhi(v1.x);
    a2 += e0 * bflo(v0.y) + e1 * bflo(v1.y);
    a3 += e0 * bfhi(v0.y) + e1 * bfhi(v1.y);
  }
  if (i < end) {
    int s = col_src[i];
    float l = as_[s * 8 + hd] + ad_d;
    l = (l > 0.f) ? l : 0.2f * l;
    float ev = __expf(l);
    denom += ev;
    uint2 v = *(const uint2*)(h + (size_t)s * 256 + c0);
    a0 += ev * bflo(v.x);
    a1 += ev * bfhi(v.x);
    a2 += ev * bflo(v.y);
    a3 += ev * bfhi(v.y);
  }
  float inv = 1.f / (denom + 1e-16f);
  float v0 = a0 * inv + bias[c0 + 0];
  float v1 = a1 * inv + bias[c0 + 1];
  float v2 = a2 * inv + bias[c0 + 2];
  float v3 = a3 * inv + bias[c0 + 3];
  v0 = (v0 > 0.f) ? v0 : expm1f(v0);
  v1 = (v1 > 0.f) ? v1 : expm1f(v1);
  v2 = (v2 > 0.f) ? v2 : expm1f(v2);
  v3 = (v3 > 0.f) ? v3 : expm1f(v3);
  ushort4 hh, ll;
  hh.x = f2bf(v0); ll.x = f2bf(v0 - bf2f(hh.x));
  hh.y = f2bf(v1); ll.y = f2bf(v1 - bf2f(hh.y));
  hh.z = f2bf(v2); ll.z = f2bf(v2 - bf2f(hh.z));
  hh.w = f2bf(v3); ll.w = f2bf(v3 - bf2f(hh.w));
  *(ushort4*)(oh + (size_t)d * 256 + c0) = hh;
  *(ushort4*)(ol + (size_t)d * 256 + c0) = ll;
}

// Layer 3: bf16 h gather, 4 dst per wave (16 lanes x 4ch), fp32 out, no ELU.
__global__ __launch_bounds__(256) void aggr_f3(
    const int* __restrict__ rowptr, const int* __restrict__ col_src,
    const ushort* __restrict__ h, const float* __restrict__ as_,
    const float* __restrict__ ad_, const float* __restrict__ bias,
    float* __restrict__ outp, int n) {
  int wid = (blockIdx.x * 256 + threadIdx.x) >> 6;
  int d = wid * 4 + ((threadIdx.x >> 4) & 3);
  if (d >= n) return;
  int l = threadIdx.x & 15;
  int c0 = l * 4;
  float ad_d = ad_[d];
  float a0 = 0.f, a1 = 0.f, a2 = 0.f, a3 = 0.f, denom = 0.f;
  int beg = rowptr[d], end = rowptr[d + 1];
  int i = beg;
  for (; i + 2 <= end; i += 2) {
    int s0 = col_src[i], s1 = col_src[i + 1];
    float l0 = as_[s0] + ad_d;
    float l1 = as_[s1] + ad_d;
    uint2 v0 = *(const uint2*)(h + (size_t)s0 * 64 + c0);
    uint2 v1 = *(const uint2*)(h + (size_t)s1 * 64 + c0);
    l0 = (l0 > 0.f) ? l0 : 0.2f * l0;
    l1 = (l1 > 0.f) ? l1 : 0.2f * l1;
    float e0 = __expf(l0), e1 = __expf(l1);
    denom += e0 + e1;
    a0 += e0 * bflo(v0.x) + e1 * bflo(v1.x);
    a1 += e0 * bfhi(v0.x) + e1 * bfhi(v1.x);
    a2 += e0 * bflo(v0.y) + e1 * bflo(v1.y);
    a3 += e0 * bfhi(v0.y) + e1 * bfhi(v1.y);
  }
  if (i < end) {
    int s = col_src[i];
    float lg = as_[s] + ad_d;
    lg = (lg > 0.f) ? lg : 0.2f * lg;
    float ev = __expf(lg);
    denom += ev;
    uint2 v = *(const uint2*)(h + (size_t)s * 64 + c0);
    a0 += ev * bflo(v.x);
    a1 += ev * bfhi(v.x);
    a2 += ev * bflo(v.y);
    a3 += ev * bfhi(v.y);
  }
  float inv = 1.f / (denom + 1e-16f);
  float4 r;
  r.x = a0 * inv + bias[c0 + 0];
  r.y = a1 * inv + bias[c0 + 1];
  r.z = a2 * inv + bias[c0 + 2];
  r.w = a3 * inv + bias[c0 + 3];
  *(float4*)(outp + (size_t)d * 64 + c0) = r;
}

// ---------------------------------------------------------------------------

extern "C" void kernel_launch(void* const* d_in, const int* in_sizes, int n_in,
                              void* d_out, int out_size, void* d_ws, size_t ws_size,
                              hipStream_t stream) {
  const float* x   = (const float*)d_in[0];
  const int*   ei  = (const int*)d_in[1];
  const float* W1  = (const float*)d_in[2];
  const float* aS1 = (const float*)d_in[3];
  const float* aD1 = (const float*)d_in[4];
  const float* b1  = (const float*)d_in[5];
  const float* W2  = (const float*)d_in[6];
  const float* aS2 = (const float*)d_in[7];
  const float* aD2 = (const float*)d_in[8];
  const float* b2  = (const float*)d_in[9];
  const float* W3  = (const float*)d_in[10];
  const float* aS3 = (const float*)d_in[11];
  const float* aD3 = (const float*)d_in[12];
  const float* b3  = (const float*)d_in[13];

  const int* srcp = ei;
  const int* dstp = ei + NEDGES;

  // ---- arena (~110 MB) ----
  char* base = (char*)d_ws;
  size_t o = 0;
  ushort* hbf  = (ushort*)(base + o); o += 25600000;   // h: N*256 bf16 / N*64 bf16
  ushort* fh   = (ushort*)(base + o); o += 25600000;   // feat hi
  ushort* fl   = (ushort*)(base + o); o += 25600000;   // feat lo
  ushort* f1h  = (ushort*)(base + o); o += 12800000;   // layer-1 input hi
  ushort* f1l  = (ushort*)(base + o); o += 12800000;   // layer-1 input lo
  float*  as_  = (float*)(base + o);  o += 1600000;
  float*  ad_  = (float*)(base + o);  o += 1600000;
  ushort* w1h  = (ushort*)(base + o); o += 65536;
  ushort* w1l  = (ushort*)(base + o); o += 65536;
  ushort* w2h  = (ushort*)(base + o); o += 131072;
  ushort* w2l  = (ushort*)(base + o); o += 131072;
  ushort* w3h  = (ushort*)(base + o); o += 32768;
  ushort* w3l  = (ushort*)(base + o); o += 32768;
  int* rowptr  = (int*)(base + o);    o += 200016;
  int* cursor  = (int*)(base + o);    o += 200000;
  int* colsrc  = (int*)(base + o);    o += 3200000;
  int* bsum    = (int*)(base + o);    o += 1024;
  float* outp  = (float*)d_out;

  // ---- CSR build (edge structure shared by all 3 layers) ----
  hipMemsetAsync(cursor, 0, NNODES * sizeof(int), stream);
  deg_kernel<<<(NEDGES + 255) / 256, 256, 0, stream>>>(dstp, cursor, NEDGES);
  int nb = (NNODES + 1023) / 1024;  // 49
  scan_partial<<<nb, 256, 0, stream>>>(cursor, rowptr, bsum, NNODES);
  scan_blocksums<<<1, 256, 0, stream>>>(bsum, nb);
  scan_add<<<(NNODES + 256) / 256, 256, 0, stream>>>(rowptr, bsum, cursor, NNODES, NEDGES);
  scatter_kernel<<<(NEDGES + 255) / 256, 256, 0, stream>>>(srcp, dstp, rowptr, cursor,
                                                           colsrc, NEDGES);

  // ---- weight / input conversions ----
  cvt_split<<<(NNODES * 128 / 4 + 255) / 256, 256, 0, stream>>>(x, f1h, f1l,
                                                                NNODES * 128 / 4);
  cvt_w<<<(128 * 256 + 255) / 256, 256, 0, stream>>>(W1, w1h, w1l, 128, 256);
  cvt_w<<<(256 * 256 + 255) / 256, 256, 0, stream>>>(W2, w2h, w2l, 256, 256);
  cvt_w<<<(256 * 64 + 255) / 256, 256, 0, stream>>>(W3, w3h, w3l, 256, 64);

  const int ga  = (NNODES + 3) / 4;    // aggr_bf: 4 dst per 256-thr block
  const int ga4 = (NNODES + 15) / 16;  // aggr_f3: 16 dst per block
  const int gw  = (NNODES + 63) / 64;  // gemm_wide grid
  // ---- layer 1: x -> fh/fl ----
  gemm_wide<<<gw, 256, 0, stream>>>(f1h, f1l, w1h, w1l, aS1, aD1, as_, ad_,
                                    hbf, NNODES, 128);
  aggr_bf<<<ga, 256, 0, stream>>>(rowptr, colsrc, hbf, as_, ad_, b1, fh, fl, NNODES);
  // ---- layer 2: fh/fl -> fh/fl ----
  gemm_wide<<<gw, 256, 0, stream>>>(fh, fl, w2h, w2l, aS2, aD2, as_, ad_,
                                    hbf, NNODES, 256);
  aggr_bf<<<ga, 256, 0, stream>>>(rowptr, colsrc, hbf, as_, ad_, b2, fh, fl, NNODES);
  // ---- layer 3: fh/fl -> d_out (bf16 h gather, fp32 accum/out) ----
  gemm_mfma3<<<dim3(1, (NNODES + 127) / 128), 256, 0, stream>>>(
      fh, fl, w3h, w3l, aS3, aD3, as_, ad_, hbf, NNODES, 256, 64);
  aggr_f3<<<ga4, 256, 0, stream>>>(rowptr, colsrc, hbf, as_, ad_, b3, outp, NNODES);
}

// Round 7
// 345.412 us; speedup vs baseline: 17.4956x; 1.0995x over previous
//
#include <hip/hip_runtime.h>
#include <hip/hip_bf16.h>
#include <hip/hip_fp16.h>
#include <stdint.h>

#define NNODES 50000
#define NEDGES 800000

typedef float f32x4 __attribute__((ext_vector_type(4)));
typedef _Float16 half8 __attribute__((ext_vector_type(8)));

__device__ __forceinline__ ushort f2h(float f) {
  return __half_as_ushort(__float2half(f));  // RNE
}
__device__ __forceinline__ float2 h2x2(uint32_t u) {
  return __half22float2(__builtin_bit_cast(__half2, u));
}

__device__ __forceinline__ void gload_lds16(const void* g, void* l) {
  __builtin_amdgcn_global_load_lds(
      (const __attribute__((address_space(1))) uint32_t*)g,
      (__attribute__((address_space(3))) uint32_t*)l, 16, 0, 0);
}

// ---------------------------------------------------------------------------
// fp16 MFMA GEMM, layers 1/2: C[M,256] = A @ Wt^T, fused alpha epilogue.
// BM=64, BN=256 (full width -> A panel read once), BK=64. fp16 out.
// XOR slot swizzle (slot ^= row&7, 8 x 16B slots per 128B row) on both the
// stage-source k-offset and the ds_read slot (rule #21).
// ---------------------------------------------------------------------------
__global__ __launch_bounds__(256) void gemm_wide(
    const ushort* __restrict__ A, const ushort* __restrict__ B,
    const float* __restrict__ a_src, const float* __restrict__ a_dst,
    float* __restrict__ as_out, float* __restrict__ ad_out,
    ushort* __restrict__ Cout, int M, int K) {
  __shared__ ushort As[64 * 64];    // 8 KB
  __shared__ ushort Bs[256 * 64];   // 32 KB

  const int t = threadIdx.x;
  const int w = t >> 6, ln = t & 63;
  const int row0 = blockIdx.x * 64;
  const int wr = (w >> 1) * 32, wc = (w & 1) * 128;

  f32x4 acc[2][8] = {};

  const int nkt = K >> 6;
  for (int kt = 0; kt < nkt; ++kt) {
    const int k0 = kt << 6;
    // stage A: 64 rows x 64 k = 8KB -> 2 instr/wave (8 rows each)
    #pragma unroll
    for (int i = 0; i < 2; ++i) {
      int row8 = w * 2 + i;
      int rloc = row8 * 8 + (ln >> 3);
      int slot = (ln & 7) ^ (rloc & 7);
      int grow = row0 + rloc; grow = grow < M ? grow : M - 1;
      gload_lds16(A + (size_t)grow * K + k0 + slot * 8, As + row8 * 512);
    }
    // stage B: 256 rows x 64 k = 32KB -> 8 instr/wave
    #pragma unroll
    for (int i = 0; i < 8; ++i) {
      int row8 = w * 8 + i;
      int rloc = row8 * 8 + (ln >> 3);
      int slot = (ln & 7) ^ (rloc & 7);
      gload_lds16(B + (size_t)rloc * K + k0 + slot * 8, Bs + row8 * 512);
    }
    __syncthreads();

    #pragma unroll
    for (int ks = 0; ks < 2; ++ks) {
      half8 a[2], b[8];
      #pragma unroll
      for (int i = 0; i < 2; ++i) {
        int row = wr + i * 16 + (ln & 15);
        int slot = (ks * 4 + (ln >> 4)) ^ (row & 7);
        a[i] = *(const half8*)(As + row * 64 + slot * 8);
      }
      #pragma unroll
      for (int j = 0; j < 8; ++j) {
        int col = wc + j * 16 + (ln & 15);
        int slot = (ks * 4 + (ln >> 4)) ^ (col & 7);
        b[j] = *(const half8*)(Bs + col * 64 + slot * 8);
      }
      #pragma unroll
      for (int i = 0; i < 2; ++i)
        #pragma unroll
        for (int j = 0; j < 8; ++j)
          acc[i][j] = __builtin_amdgcn_mfma_f32_16x16x32_f16(a[i], b[j], acc[i][j], 0, 0, 0);
    }
    __syncthreads();
  }

  const int lx = ln & 15, g = ln >> 4;

  // ---- C write (C/D layout: col=lane&15, row=(lane>>4)*4+reg) ----
  #pragma unroll
  for (int i = 0; i < 2; ++i)
    #pragma unroll
    for (int j = 0; j < 8; ++j)
      #pragma unroll
      for (int r = 0; r < 4; ++r) {
        int grow = row0 + wr + i * 16 + g * 4 + r;
        int gcol = wc + j * 16 + lx;
        if (grow < M) Cout[(size_t)grow * 256 + gcol] = f2h(acc[i][j][r]);
      }

  // ---- fused alpha epilogue (fp32 acc; heads disjoint across col-waves) ----
  const int hbase = wc >> 5;  // heads 0-3 (wc=0) or 4-7 (wc=128)
  float avs[8], avd[8];
  #pragma unroll
  for (int j = 0; j < 8; ++j) {
    avs[j] = a_src[wc + j * 16 + lx];
    avd[j] = a_dst[wc + j * 16 + lx];
  }
  #pragma unroll
  for (int i = 0; i < 2; ++i)
    #pragma unroll
    for (int r = 0; r < 4; ++r) {
      float ps[4] = {0.f, 0.f, 0.f, 0.f}, pd[4] = {0.f, 0.f, 0.f, 0.f};
      #pragma unroll
      for (int j = 0; j < 8; ++j) {
        float v = acc[i][j][r];
        ps[j >> 1] += v * avs[j];
        pd[j >> 1] += v * avd[j];
      }
      #pragma unroll
      for (int m = 1; m < 16; m <<= 1)
        #pragma unroll
        for (int q = 0; q < 4; ++q) {
          ps[q] += __shfl_xor(ps[q], m);
          pd[q] += __shfl_xor(pd[q], m);
        }
      if (lx == 0) {
        int grow = row0 + wr + i * 16 + g * 4 + r;
        if (grow < M) {
          #pragma unroll
          for (int q = 0; q < 4; ++q) {
            as_out[grow * 8 + hbase + q] = ps[q];
            ad_out[grow * 8 + hbase + q] = pd[q];
          }
        }
      }
    }
}

// ---------------------------------------------------------------------------
// fp16 MFMA GEMM, layer 3 (Ncols=64): BM=128, BN=64, BK=64. fp16 out.
// FUSED alpha (H=1, C=64): 16-lane shfl reduce + LDS combine across col-waves.
// ---------------------------------------------------------------------------
__global__ __launch_bounds__(256) void gemm_mfma3(
    const ushort* __restrict__ A, const ushort* __restrict__ B,
    const float* __restrict__ a_src, const float* __restrict__ a_dst,
    float* __restrict__ as_out, float* __restrict__ ad_out,
    ushort* __restrict__ Cout, int M, int K, int Ncols) {
  __shared__ ushort As[128 * 64];   // 16 KB
  __shared__ ushort Bs[64 * 64];    // 8 KB
  __shared__ float redS[2][128], redD[2][128];

  const int t = threadIdx.x;
  const int w = t >> 6, ln = t & 63;
  const int row0 = blockIdx.y * 128;
  const int col0 = blockIdx.x * 64;
  const int wr = (w >> 1) * 64, wc = (w & 1) * 32;

  f32x4 acc[4][2] = {};

  const int nkt = K >> 6;
  for (int kt = 0; kt < nkt; ++kt) {
    const int k0 = kt << 6;
    #pragma unroll
    for (int i = 0; i < 4; ++i) {
      int row8 = w * 4 + i;
      int rloc = row8 * 8 + (ln >> 3);
      int slot = (ln & 7) ^ (rloc & 7);
      int grow = row0 + rloc; grow = grow < M ? grow : M - 1;
      gload_lds16(A + (size_t)grow * K + k0 + slot * 8, As + row8 * 512);
    }
    #pragma unroll
    for (int i = 0; i < 2; ++i) {
      int row8 = w * 2 + i;
      int rloc = row8 * 8 + (ln >> 3);
      int slot = (ln & 7) ^ (rloc & 7);
      gload_lds16(B + (size_t)(col0 + rloc) * K + k0 + slot * 8, Bs + row8 * 512);
    }
    __syncthreads();

    #pragma unroll
    for (int ks = 0; ks < 2; ++ks) {
      half8 a[4], b[2];
      #pragma unroll
      for (int i = 0; i < 4; ++i) {
        int row = wr + i * 16 + (ln & 15);
        int slot = (ks * 4 + (ln >> 4)) ^ (row & 7);
        a[i] = *(const half8*)(As + row * 64 + slot * 8);
      }
      #pragma unroll
      for (int j = 0; j < 2; ++j) {
        int col = wc + j * 16 + (ln & 15);
        int slot = (ks * 4 + (ln >> 4)) ^ (col & 7);
        b[j] = *(const half8*)(Bs + col * 64 + slot * 8);
      }
      #pragma unroll
      for (int i = 0; i < 4; ++i)
        #pragma unroll
        for (int j = 0; j < 2; ++j)
          acc[i][j] = __builtin_amdgcn_mfma_f32_16x16x32_f16(a[i], b[j], acc[i][j], 0, 0, 0);
    }
    __syncthreads();
  }

  const int lx = ln & 15, g = ln >> 4;

  #pragma unroll
  for (int i = 0; i < 4; ++i)
    #pragma unroll
    for (int j = 0; j < 2; ++j)
      #pragma unroll
      for (int r = 0; r < 4; ++r) {
        int grow = row0 + wr + i * 16 + g * 4 + r;
        int gcol = col0 + wc + j * 16 + lx;
        if (grow < M) Cout[(size_t)grow * Ncols + gcol] = f2h(acc[i][j][r]);
      }

  // ---- fused alpha (single head over 64 cols) ----
  float avs[2], avd[2];
  #pragma unroll
  for (int j = 0; j < 2; ++j) {
    avs[j] = a_src[wc + j * 16 + lx];
    avd[j] = a_dst[wc + j * 16 + lx];
  }
  #pragma unroll
  for (int i = 0; i < 4; ++i)
    #pragma unroll
    for (int r = 0; r < 4; ++r) {
      float ps = 0.f, pd = 0.f;
      #pragma unroll
      for (int j = 0; j < 2; ++j) {
        float v = acc[i][j][r];
        ps += v * avs[j];
        pd += v * avd[j];
      }
      #pragma unroll
      for (int m = 1; m < 16; m <<= 1) {
        ps += __shfl_xor(ps, m);
        pd += __shfl_xor(pd, m);
      }
      if (lx == 0) {
        int lrow = wr + i * 16 + g * 4 + r;  // 0..127
        redS[w & 1][lrow] = ps;
        redD[w & 1][lrow] = pd;
      }
    }
  __syncthreads();
  if (t < 128) {
    int grow = row0 + t;
    if (grow < M) {
      as_out[grow] = redS[0][t] + redS[1][t];
      ad_out[grow] = redD[0][t] + redD[1][t];
    }
  }
}

// ---------------------------------------------------------------------------
// fp32 -> fp16 convert (float4-vectorized)
// ---------------------------------------------------------------------------
__global__ void cvt_h(const float* __restrict__ in, ushort* __restrict__ out, int n4) {
  int idx = blockIdx.x * blockDim.x + threadIdx.x;
  if (idx >= n4) return;
  float4 v = ((const float4*)in)[idx];
  ushort4 o;
  o.x = f2h(v.x); o.y = f2h(v.y); o.z = f2h(v.z); o.w = f2h(v.w);
  ((ushort4*)out)[idx] = o;
}

// W [K][N] fp32 -> Wt [N][K] fp16 (tiny)
__global__ void cvt_w(const float* __restrict__ W, ushort* __restrict__ tr,
                      int K, int N) {
  int idx = blockIdx.x * blockDim.x + threadIdx.x;
  if (idx >= K * N) return;
  int k = idx / N, c = idx - k * N;
  tr[(size_t)c * K + k] = f2h(W[idx]);
}

// ---------------------------------------------------------------------------
// CSR build
// ---------------------------------------------------------------------------
__global__ void deg_kernel(const int* __restrict__ dst, int* __restrict__ deg, int E) {
  int e = blockIdx.x * blockDim.x + threadIdx.x;
  if (e < E) atomicAdd(&deg[dst[e]], 1);
}

__global__ __launch_bounds__(256) void scan_partial(const int* __restrict__ deg,
                                                    int* __restrict__ rowptr,
                                                    int* __restrict__ blocksum, int n) {
  __shared__ int sdata[256];
  int t = threadIdx.x;
  int base = blockIdx.x * 1024 + t * 4;
  int v[4], s = 0;
  #pragma unroll
  for (int i = 0; i < 4; ++i) {
    v[i] = (base + i < n) ? deg[base + i] : 0;
    s += v[i];
  }
  sdata[t] = s;
  __syncthreads();
  for (int off = 1; off < 256; off <<= 1) {
    int x = (t >= off) ? sdata[t - off] : 0;
    __syncthreads();
    sdata[t] += x;
    __syncthreads();
  }
  int run = sdata[t] - s;
  #pragma unroll
  for (int i = 0; i < 4; ++i) {
    if (base + i < n) rowptr[base + i] = run;
    run += v[i];
  }
  if (t == 255) blocksum[blockIdx.x] = sdata[255];
}

__global__ __launch_bounds__(256) void scan_blocksums(int* __restrict__ blocksum, int nb) {
  __shared__ int sdata[256];
  int t = threadIdx.x;
  int v = (t < nb) ? blocksum[t] : 0;
  sdata[t] = v;
  __syncthreads();
  for (int off = 1; off < 256; off <<= 1) {
    int x = (t >= off) ? sdata[t - off] : 0;
    __syncthreads();
    sdata[t] += x;
    __syncthreads();
  }
  if (t < nb) blocksum[t] = sdata[t] - v;
}

// also re-zeroes cursor for the scatter pass
__global__ void scan_add(int* __restrict__ rowptr, const int* __restrict__ blocksum,
                         int* __restrict__ cursor, int n, int E) {
  int idx = blockIdx.x * blockDim.x + threadIdx.x;
  if (idx < n) {
    rowptr[idx] += blocksum[idx >> 10];
    cursor[idx] = 0;
  }
  if (idx == n) rowptr[n] = E;
}

__global__ void scatter_kernel(const int* __restrict__ src, const int* __restrict__ dst,
                               const int* __restrict__ rowptr, int* __restrict__ cursor,
                               int* __restrict__ col_src, int E) {
  int e = blockIdx.x * blockDim.x + threadIdx.x;
  if (e >= E) return;
  int d = dst[e];
  int pos = rowptr[d] + atomicAdd(&cursor[d], 1);
  col_src[pos] = src[e];
}

// ---------------------------------------------------------------------------
// Fused per-dst softmax + aggregate, 1 dst/wave, 2-edge unroll (r4 form).
// fp16 h gather, fp16 feat output with bias+ELU.
// ---------------------------------------------------------------------------
__global__ __launch_bounds__(256) void aggr_h(
    const int* __restrict__ rowptr, const int* __restrict__ col_src,
    const ushort* __restrict__ h, const float* __restrict__ as_,
    const float* __restrict__ ad_, const float* __restrict__ bias,
    ushort* __restrict__ of, int n) {
  int d = blockIdx.x * 4 + (threadIdx.x >> 6);
  if (d >= n) return;
  int lane = threadIdx.x & 63;
  int c0 = lane * 4;
  int hd = lane >> 3;  // c0 / 32
  float ad_d = ad_[d * 8 + hd];
  float a0 = 0.f, a1 = 0.f, a2 = 0.f, a3 = 0.f, denom = 0.f;
  int beg = rowptr[d], end = rowptr[d + 1];
  int i = beg;
  for (; i + 2 <= end; i += 2) {
    int s0 = col_src[i], s1 = col_src[i + 1];
    float l0 = as_[s0 * 8 + hd] + ad_d;
    float l1 = as_[s1 * 8 + hd] + ad_d;
    uint2 v0 = *(const uint2*)(h + (size_t)s0 * 256 + c0);
    uint2 v1 = *(const uint2*)(h + (size_t)s1 * 256 + c0);
    l0 = (l0 > 0.f) ? l0 : 0.2f * l0;
    l1 = (l1 > 0.f) ? l1 : 0.2f * l1;
    float e0 = __expf(l0), e1 = __expf(l1);
    denom += e0 + e1;
    float2 p0 = h2x2(v0.x), p1 = h2x2(v0.y);
    float2 q0 = h2x2(v1.x), q1 = h2x2(v1.y);
    a0 += e0 * p0.x + e1 * q0.x;
    a1 += e0 * p0.y + e1 * q0.y;
    a2 += e0 * p1.x + e1 * q1.x;
    a3 += e0 * p1.y + e1 * q1.y;
  }
  if (i < end) {
    int s = col_src[i];
    float l = as_[s * 8 + hd] + ad_d;
    l = (l > 0.f) ? l : 0.2f * l;
    float ev = __expf(l);
    denom += ev;
    uint2 v = *(const uint2*)(h + (size_t)s * 256 + c0);
    float2 p0 = h2x2(v.x), p1 = h2x2(v.y);
    a0 += ev * p0.x;
    a1 += ev * p0.y;
    a2 += ev * p1.x;
    a3 += ev * p1.y;
  }
  float inv = 1.f / (denom + 1e-16f);
  float v0 = a0 * inv + bias[c0 + 0];
  float v1 = a1 * inv + bias[c0 + 1];
  float v2 = a2 * inv + bias[c0 + 2];
  float v3 = a3 * inv + bias[c0 + 3];
  v0 = (v0 > 0.f) ? v0 : expm1f(v0);
  v1 = (v1 > 0.f) ? v1 : expm1f(v1);
  v2 = (v2 > 0.f) ? v2 : expm1f(v2);
  v3 = (v3 > 0.f) ? v3 : expm1f(v3);
  ushort4 hh;
  hh.x = f2h(v0); hh.y = f2h(v1); hh.z = f2h(v2); hh.w = f2h(v3);
  *(ushort4*)(of + (size_t)d * 256 + c0) = hh;
}

// Layer 3: fp16 h gather, 4 dst per wave (16 lanes x 4ch), fp32 out, no ELU.
__global__ __launch_bounds__(256) void aggr_f3(
    const int* __restrict__ rowptr, const int* __restrict__ col_src,
    const ushort* __restrict__ h, const float* __restrict__ as_,
    const float* __restrict__ ad_, const float* __restrict__ bias,
    float* __restrict__ outp, int n) {
  int wid = (blockIdx.x * 256 + threadIdx.x) >> 6;
  int d = wid * 4 + ((threadIdx.x >> 4) & 3);
  if (d >= n) return;
  int l = threadIdx.x & 15;
  int c0 = l * 4;
  float ad_d = ad_[d];
  float a0 = 0.f, a1 = 0.f, a2 = 0.f, a3 = 0.f, denom = 0.f;
  int beg = rowptr[d], end = rowptr[d + 1];
  int i = beg;
  for (; i + 2 <= end; i += 2) {
    int s0 = col_src[i], s1 = col_src[i + 1];
    float l0 = as_[s0] + ad_d;
    float l1 = as_[s1] + ad_d;
    uint2 v0 = *(const uint2*)(h + (size_t)s0 * 64 + c0);
    uint2 v1 = *(const uint2*)(h + (size_t)s1 * 64 + c0);
    l0 = (l0 > 0.f) ? l0 : 0.2f * l0;
    l1 = (l1 > 0.f) ? l1 : 0.2f * l1;
    float e0 = __expf(l0), e1 = __expf(l1);
    denom += e0 + e1;
    float2 p0 = h2x2(v0.x), p1 = h2x2(v0.y);
    float2 q0 = h2x2(v1.x), q1 = h2x2(v1.y);
    a0 += e0 * p0.x + e1 * q0.x;
    a1 += e0 * p0.y + e1 * q0.y;
    a2 += e0 * p1.x + e1 * q1.x;
    a3 += e0 * p1.y + e1 * q1.y;
  }
  if (i < end) {
    int s = col_src[i];
    float lg = as_[s] + ad_d;
    lg = (lg > 0.f) ? lg : 0.2f * lg;
    float ev = __expf(lg);
    denom += ev;
    uint2 v = *(const uint2*)(h + (size_t)s * 64 + c0);
    float2 p0 = h2x2(v.x), p1 = h2x2(v.y);
    a0 += ev * p0.x;
    a1 += ev * p0.y;
    a2 += ev * p1.x;
    a3 += ev * p1.y;
  }
  float inv = 1.f / (denom + 1e-16f);
  float4 r;
  r.x = a0 * inv + bias[c0 + 0];
  r.y = a1 * inv + bias[c0 + 1];
  r.z = a2 * inv + bias[c0 + 2];
  r.w = a3 * inv + bias[c0 + 3];
  *(float4*)(outp + (size_t)d * 64 + c0) = r;
}

// ---------------------------------------------------------------------------

extern "C" void kernel_launch(void* const* d_in, const int* in_sizes, int n_in,
                              void* d_out, int out_size, void* d_ws, size_t ws_size,
                              hipStream_t stream) {
  const float* x   = (const float*)d_in[0];
  const int*   ei  = (const int*)d_in[1];
  const float* W1  = (const float*)d_in[2];
  const float* aS1 = (const float*)d_in[3];
  const float* aD1 = (const float*)d_in[4];
  const float* b1  = (const float*)d_in[5];
  const float* W2  = (const float*)d_in[6];
  const float* aS2 = (const float*)d_in[7];
  const float* aD2 = (const float*)d_in[8];
  const float* b2  = (const float*)d_in[9];
  const float* W3  = (const float*)d_in[10];
  const float* aS3 = (const float*)d_in[11];
  const float* aD3 = (const float*)d_in[12];
  const float* b3  = (const float*)d_in[13];

  const int* srcp = ei;
  const int* dstp = ei + NEDGES;

  // ---- arena (~72 MB) ----
  char* base = (char*)d_ws;
  size_t o = 0;
  ushort* hbf  = (ushort*)(base + o); o += 25600000;   // h: N*256 fp16 / N*64 fp16
  ushort* ff   = (ushort*)(base + o); o += 25600000;   // feat fp16 (layers 2/3 in)
  ushort* f1   = (ushort*)(base + o); o += 12800000;   // layer-1 input fp16
  float*  as_  = (float*)(base + o);  o += 1600000;
  float*  ad_  = (float*)(base + o);  o += 1600000;
  ushort* w1t  = (ushort*)(base + o); o += 65536;      // 256x128 fp16
  ushort* w2t  = (ushort*)(base + o); o += 131072;     // 256x256 fp16
  ushort* w3t  = (ushort*)(base + o); o += 32768;      // 64x256 fp16
  int* rowptr  = (int*)(base + o);    o += 200016;
  int* cursor  = (int*)(base + o);    o += 200000;
  int* colsrc  = (int*)(base + o);    o += 3200000;
  int* bsum    = (int*)(base + o);    o += 1024;
  float* outp  = (float*)d_out;

  // ---- CSR build (edge structure shared by all 3 layers) ----
  hipMemsetAsync(cursor, 0, NNODES * sizeof(int), stream);
  deg_kernel<<<(NEDGES + 255) / 256, 256, 0, stream>>>(dstp, cursor, NEDGES);
  int nb = (NNODES + 1023) / 1024;  // 49
  scan_partial<<<nb, 256, 0, stream>>>(cursor, rowptr, bsum, NNODES);
  scan_blocksums<<<1, 256, 0, stream>>>(bsum, nb);
  scan_add<<<(NNODES + 256) / 256, 256, 0, stream>>>(rowptr, bsum, cursor, NNODES, NEDGES);
  scatter_kernel<<<(NEDGES + 255) / 256, 256, 0, stream>>>(srcp, dstp, rowptr, cursor,
                                                           colsrc, NEDGES);

  // ---- weight / input conversions ----
  cvt_h<<<(NNODES * 128 / 4 + 255) / 256, 256, 0, stream>>>(x, f1, NNODES * 128 / 4);
  cvt_w<<<(128 * 256 + 255) / 256, 256, 0, stream>>>(W1, w1t, 128, 256);
  cvt_w<<<(256 * 256 + 255) / 256, 256, 0, stream>>>(W2, w2t, 256, 256);
  cvt_w<<<(256 * 64 + 255) / 256, 256, 0, stream>>>(W3, w3t, 256, 64);

  const int ga  = (NNODES + 3) / 4;    // aggr_h: 4 dst per 256-thr block
  const int ga4 = (NNODES + 15) / 16;  // aggr_f3: 16 dst per block
  const int gw  = (NNODES + 63) / 64;  // gemm_wide grid
  // ---- layer 1: x -> ff ----
  gemm_wide<<<gw, 256, 0, stream>>>(f1, w1t, aS1, aD1, as_, ad_, hbf, NNODES, 128);
  aggr_h<<<ga, 256, 0, stream>>>(rowptr, colsrc, hbf, as_, ad_, b1, ff, NNODES);
  // ---- layer 2: ff -> ff (h in hbf; aggr overwrites ff after GEMM read) ----
  gemm_wide<<<gw, 256, 0, stream>>>(ff, w2t, aS2, aD2, as_, ad_, hbf, NNODES, 256);
  aggr_h<<<ga, 256, 0, stream>>>(rowptr, colsrc, hbf, as_, ad_, b2, ff, NNODES);
  // ---- layer 3: ff -> d_out ----
  gemm_mfma3<<<dim3(1, (NNODES + 127) / 128), 256, 0, stream>>>(
      ff, w3t, aS3, aD3, as_, ad_, hbf, NNODES, 256, 64);
  aggr_f3<<<ga4, 256, 0, stream>>>(rowptr, colsrc, hbf, as_, ad_, b3, outp, NNODES);
}

// Round 9
// 330.467 us; speedup vs baseline: 18.2868x; 1.0452x over previous
//
#include <hip/hip_runtime.h>
#include <hip/hip_bf16.h>
#include <hip/hip_fp16.h>
#include <stdint.h>

#define NNODES 50000
#define NEDGES 800000
#define LOG2E 1.44269504088896340736f

typedef float f32x4 __attribute__((ext_vector_type(4)));
typedef _Float16 half8 __attribute__((ext_vector_type(8)));
typedef _Float16 half2v __attribute__((ext_vector_type(2)));

__device__ __forceinline__ ushort f2h(float f) {
  return __half_as_ushort(__float2half(f));  // RNE
}
__device__ __forceinline__ float2 h2x2(uint32_t u) {
  return __half22float2(__builtin_bit_cast(__half2, u));
}

#if __has_builtin(__builtin_amdgcn_fdot2) && __has_builtin(__builtin_amdgcn_perm) && __has_builtin(__builtin_amdgcn_cvt_pkrtz)
#define USE_DOT2 1
#else
#define USE_DOT2 0
#endif

__device__ __forceinline__ half2v pack2(float a, float b) {
  return __builtin_bit_cast(half2v, __builtin_amdgcn_cvt_pkrtz(a, b));
}

__device__ __forceinline__ float fexp2(float x) {
#if __has_builtin(__builtin_amdgcn_exp2f)
  return __builtin_amdgcn_exp2f(x);
#else
  return exp2f(x);
#endif
}

__device__ __forceinline__ void gload_lds16(const void* g, void* l) {
  __builtin_amdgcn_global_load_lds(
      (const __attribute__((address_space(1))) uint32_t*)g,
      (__attribute__((address_space(3))) uint32_t*)l, 16, 0, 0);
}

// ---------------------------------------------------------------------------
// fp16 MFMA GEMM, layers 1/2: C[M,256] = A @ Wt^T, fused alpha epilogue.
// BM=64, BN=256 (A panel read once), BK=64. fp16 out.
// alpha outputs pre-scaled by LOG2E so aggr can use v_exp_f32 directly.
// ---------------------------------------------------------------------------
__global__ __launch_bounds__(256) void gemm_wide(
    const ushort* __restrict__ A, const ushort* __restrict__ B,
    const float* __restrict__ a_src, const float* __restrict__ a_dst,
    float* __restrict__ as_out, float* __restrict__ ad_out,
    ushort* __restrict__ Cout, int M, int K) {
  __shared__ ushort As[64 * 64];    // 8 KB
  __shared__ ushort Bs[256 * 64];   // 32 KB

  const int t = threadIdx.x;
  const int w = t >> 6, ln = t & 63;
  const int row0 = blockIdx.x * 64;
  const int wr = (w >> 1) * 32, wc = (w & 1) * 128;

  f32x4 acc[2][8] = {};

  const int nkt = K >> 6;
  for (int kt = 0; kt < nkt; ++kt) {
    const int k0 = kt << 6;
    #pragma unroll
    for (int i = 0; i < 2; ++i) {
      int row8 = w * 2 + i;
      int rloc = row8 * 8 + (ln >> 3);
      int slot = (ln & 7) ^ (rloc & 7);
      int grow = row0 + rloc; grow = grow < M ? grow : M - 1;
      gload_lds16(A + (size_t)grow * K + k0 + slot * 8, As + row8 * 512);
    }
    #pragma unroll
    for (int i = 0; i < 8; ++i) {
      int row8 = w * 8 + i;
      int rloc = row8 * 8 + (ln >> 3);
      int slot = (ln & 7) ^ (rloc & 7);
      gload_lds16(B + (size_t)rloc * K + k0 + slot * 8, Bs + row8 * 512);
    }
    __syncthreads();

    #pragma unroll
    for (int ks = 0; ks < 2; ++ks) {
      half8 a[2], b[8];
      #pragma unroll
      for (int i = 0; i < 2; ++i) {
        int row = wr + i * 16 + (ln & 15);
        int slot = (ks * 4 + (ln >> 4)) ^ (row & 7);
        a[i] = *(const half8*)(As + row * 64 + slot * 8);
      }
      #pragma unroll
      for (int j = 0; j < 8; ++j) {
        int col = wc + j * 16 + (ln & 15);
        int slot = (ks * 4 + (ln >> 4)) ^ (col & 7);
        b[j] = *(const half8*)(Bs + col * 64 + slot * 8);
      }
      #pragma unroll
      for (int i = 0; i < 2; ++i)
        #pragma unroll
        for (int j = 0; j < 8; ++j)
          acc[i][j] = __builtin_amdgcn_mfma_f32_16x16x32_f16(a[i], b[j], acc[i][j], 0, 0, 0);
    }
    __syncthreads();
  }

  const int lx = ln & 15, g = ln >> 4;

  #pragma unroll
  for (int i = 0; i < 2; ++i)
    #pragma unroll
    for (int j = 0; j < 8; ++j)
      #pragma unroll
      for (int r = 0; r < 4; ++r) {
        int grow = row0 + wr + i * 16 + g * 4 + r;
        int gcol = wc + j * 16 + lx;
        if (grow < M) Cout[(size_t)grow * 256 + gcol] = f2h(acc[i][j][r]);
      }

  // ---- fused alpha epilogue (LOG2E pre-scaled) ----
  const int hbase = wc >> 5;
  float avs[8], avd[8];
  #pragma unroll
  for (int j = 0; j < 8; ++j) {
    avs[j] = a_src[wc + j * 16 + lx] * LOG2E;
    avd[j] = a_dst[wc + j * 16 + lx] * LOG2E;
  }
  #pragma unroll
  for (int i = 0; i < 2; ++i)
    #pragma unroll
    for (int r = 0; r < 4; ++r) {
      float ps[4] = {0.f, 0.f, 0.f, 0.f}, pd[4] = {0.f, 0.f, 0.f, 0.f};
      #pragma unroll
      for (int j = 0; j < 8; ++j) {
        float v = acc[i][j][r];
        ps[j >> 1] += v * avs[j];
        pd[j >> 1] += v * avd[j];
      }
      #pragma unroll
      for (int m = 1; m < 16; m <<= 1)
        #pragma unroll
        for (int q = 0; q < 4; ++q) {
          ps[q] += __shfl_xor(ps[q], m);
          pd[q] += __shfl_xor(pd[q], m);
        }
      if (lx == 0) {
        int grow = row0 + wr + i * 16 + g * 4 + r;
        if (grow < M) {
          #pragma unroll
          for (int q = 0; q < 4; ++q) {
            as_out[grow * 8 + hbase + q] = ps[q];
            ad_out[grow * 8 + hbase + q] = pd[q];
          }
        }
      }
    }
}

// ---------------------------------------------------------------------------
// fp16 MFMA GEMM, layer 3 (Ncols=64): BM=128, BN=64, BK=64. fp16 out.
// Fused alpha (H=1, C=64), LOG2E pre-scaled.
// ---------------------------------------------------------------------------
__global__ __launch_bounds__(256) void gemm_mfma3(
    const ushort* __restrict__ A, const ushort* __restrict__ B,
    const float* __restrict__ a_src, const float* __restrict__ a_dst,
    float* __restrict__ as_out, float* __restrict__ ad_out,
    ushort* __restrict__ Cout, int M, int K, int Ncols) {
  __shared__ ushort As[128 * 64];
  __shared__ ushort Bs[64 * 64];
  __shared__ float redS[2][128], redD[2][128];

  const int t = threadIdx.x;
  const int w = t >> 6, ln = t & 63;
  const int row0 = blockIdx.y * 128;
  const int col0 = blockIdx.x * 64;
  const int wr = (w >> 1) * 64, wc = (w & 1) * 32;

  f32x4 acc[4][2] = {};

  const int nkt = K >> 6;
  for (int kt = 0; kt < nkt; ++kt) {
    const int k0 = kt << 6;
    #pragma unroll
    for (int i = 0; i < 4; ++i) {
      int row8 = w * 4 + i;
      int rloc = row8 * 8 + (ln >> 3);
      int slot = (ln & 7) ^ (rloc & 7);
      int grow = row0 + rloc; grow = grow < M ? grow : M - 1;
      gload_lds16(A + (size_t)grow * K + k0 + slot * 8, As + row8 * 512);
    }
    #pragma unroll
    for (int i = 0; i < 2; ++i) {
      int row8 = w * 2 + i;
      int rloc = row8 * 8 + (ln >> 3);
      int slot = (ln & 7) ^ (rloc & 7);
      gload_lds16(B + (size_t)(col0 + rloc) * K + k0 + slot * 8, Bs + row8 * 512);
    }
    __syncthreads();

    #pragma unroll
    for (int ks = 0; ks < 2; ++ks) {
      half8 a[4], b[2];
      #pragma unroll
      for (int i = 0; i < 4; ++i) {
        int row = wr + i * 16 + (ln & 15);
        int slot = (ks * 4 + (ln >> 4)) ^ (row & 7);
        a[i] = *(const half8*)(As + row * 64 + slot * 8);
      }
      #pragma unroll
      for (int j = 0; j < 2; ++j) {
        int col = wc + j * 16 + (ln & 15);
        int slot = (ks * 4 + (ln >> 4)) ^ (col & 7);
        b[j] = *(const half8*)(Bs + col * 64 + slot * 8);
      }
      #pragma unroll
      for (int i = 0; i < 4; ++i)
        #pragma unroll
        for (int j = 0; j < 2; ++j)
          acc[i][j] = __builtin_amdgcn_mfma_f32_16x16x32_f16(a[i], b[j], acc[i][j], 0, 0, 0);
    }
    __syncthreads();
  }

  const int lx = ln & 15, g = ln >> 4;

  #pragma unroll
  for (int i = 0; i < 4; ++i)
    #pragma unroll
    for (int j = 0; j < 2; ++j)
      #pragma unroll
      for (int r = 0; r < 4; ++r) {
        int grow = row0 + wr + i * 16 + g * 4 + r;
        int gcol = col0 + wc + j * 16 + lx;
        if (grow < M) Cout[(size_t)grow * Ncols + gcol] = f2h(acc[i][j][r]);
      }

  float avs[2], avd[2];
  #pragma unroll
  for (int j = 0; j < 2; ++j) {
    avs[j] = a_src[wc + j * 16 + lx] * LOG2E;
    avd[j] = a_dst[wc + j * 16 + lx] * LOG2E;
  }
  #pragma unroll
  for (int i = 0; i < 4; ++i)
    #pragma unroll
    for (int r = 0; r < 4; ++r) {
      float ps = 0.f, pd = 0.f;
      #pragma unroll
      for (int j = 0; j < 2; ++j) {
        float v = acc[i][j][r];
        ps += v * avs[j];
        pd += v * avd[j];
      }
      #pragma unroll
      for (int m = 1; m < 16; m <<= 1) {
        ps += __shfl_xor(ps, m);
        pd += __shfl_xor(pd, m);
      }
      if (lx == 0) {
        int lrow = wr + i * 16 + g * 4 + r;
        redS[w & 1][lrow] = ps;
        redD[w & 1][lrow] = pd;
      }
    }
  __syncthreads();
  if (t < 128) {
    int grow = row0 + t;
    if (grow < M) {
      as_out[grow] = redS[0][t] + redS[1][t];
      ad_out[grow] = redD[0][t] + redD[1][t];
    }
  }
}

// ---------------------------------------------------------------------------
__global__ void cvt_h(const float* __restrict__ in, ushort* __restrict__ out, int n4) {
  int idx = blockIdx.x * blockDim.x + threadIdx.x;
  if (idx >= n4) return;
  float4 v = ((const float4*)in)[idx];
  ushort4 o;
  o.x = f2h(v.x); o.y = f2h(v.y); o.z = f2h(v.z); o.w = f2h(v.w);
  ((ushort4*)out)[idx] = o;
}

__global__ void cvt_w(const float* __restrict__ W, ushort* __restrict__ tr,
                      int K, int N) {
  int idx = blockIdx.x * blockDim.x + threadIdx.x;
  if (idx >= K * N) return;
  int k = idx / N, c = idx - k * N;
  tr[(size_t)c * K + k] = f2h(W[idx]);
}

// ---------------------------------------------------------------------------
// CSR build
// ---------------------------------------------------------------------------
__global__ void deg_kernel(const int* __restrict__ dst, int* __restrict__ deg, int E) {
  int e = blockIdx.x * blockDim.x + threadIdx.x;
  if (e < E) atomicAdd(&deg[dst[e]], 1);
}

__global__ __launch_bounds__(256) void scan_partial(const int* __restrict__ deg,
                                                    int* __restrict__ rowptr,
                                                    int* __restrict__ blocksum, int n) {
  __shared__ int sdata[256];
  int t = threadIdx.x;
  int base = blockIdx.x * 1024 + t * 4;
  int v[4], s = 0;
  #pragma unroll
  for (int i = 0; i < 4; ++i) {
    v[i] = (base + i < n) ? deg[base + i] : 0;
    s += v[i];
  }
  sdata[t] = s;
  __syncthreads();
  for (int off = 1; off < 256; off <<= 1) {
    int x = (t >= off) ? sdata[t - off] : 0;
    __syncthreads();
    sdata[t] += x;
    __syncthreads();
  }
  int run = sdata[t] - s;
  #pragma unroll
  for (int i = 0; i < 4; ++i) {
    if (base + i < n) rowptr[base + i] = run;
    run += v[i];
  }
  if (t == 255) blocksum[blockIdx.x] = sdata[255];
}

__global__ __launch_bounds__(256) void scan_blocksums(int* __restrict__ blocksum, int nb) {
  __shared__ int sdata[256];
  int t = threadIdx.x;
  int v = (t < nb) ? blocksum[t] : 0;
  sdata[t] = v;
  __syncthreads();
  for (int off = 1; off < 256; off <<= 1) {
    int x = (t >= off) ? sdata[t - off] : 0;
    __syncthreads();
    sdata[t] += x;
    __syncthreads();
  }
  if (t < nb) blocksum[t] = sdata[t] - v;
}

__global__ void scan_add(int* __restrict__ rowptr, const int* __restrict__ blocksum,
                         int* __restrict__ cursor, int n, int E) {
  int idx = blockIdx.x * blockDim.x + threadIdx.x;
  if (idx < n) {
    rowptr[idx] += blocksum[idx >> 10];
    cursor[idx] = 0;
  }
  if (idx == n) rowptr[n] = E;
}

__global__ void scatter_kernel(const int* __restrict__ src, const int* __restrict__ dst,
                               const int* __restrict__ rowptr, int* __restrict__ cursor,
                               int* __restrict__ col_src, int E) {
  int e = blockIdx.x * blockDim.x + threadIdx.x;
  if (e >= E) return;
  int d = dst[e];
  int pos = rowptr[d] + atomicAdd(&cursor[d], 1);
  col_src[pos] = src[e];
}

// ---------------------------------------------------------------------------
// Fused per-dst softmax + aggregate, 1 dst/wave, 4-edge unroll, fdot2 MAC.
// fp16 h gather, fp16 feat output with bias+ELU. as_/ad_ are LOG2E-scaled.
// ---------------------------------------------------------------------------
__global__ __launch_bounds__(256) void aggr_h(
    const int* __restrict__ rowptr, const int* __restrict__ col_src,
    const ushort* __restrict__ h, const float* __restrict__ as_,
    const float* __restrict__ ad_, const float* __restrict__ bias,
    ushort* __restrict__ of, int n) {
  int d = blockIdx.x * 4 + (threadIdx.x >> 6);
  if (d >= n) return;
  int lane = threadIdx.x & 63;
  int c0 = lane * 4;
  int hd = lane >> 3;
  float ad_d = ad_[d * 8 + hd];
  float a0 = 0.f, a1 = 0.f, a2 = 0.f, a3 = 0.f, denom = 0.f;
  const ushort* hp = h + c0;
  int beg = rowptr[d], end = rowptr[d + 1];
  int i = beg;
#if USE_DOT2
  const half2v onepk = {(_Float16)1.f, (_Float16)1.f};
  for (; i + 4 <= end; i += 4) {
    int s0 = col_src[i], s1 = col_src[i + 1], s2 = col_src[i + 2], s3 = col_src[i + 3];
    float l0 = as_[s0 * 8 + hd] + ad_d;
    float l1 = as_[s1 * 8 + hd] + ad_d;
    float l2 = as_[s2 * 8 + hd] + ad_d;
    float l3 = as_[s3 * 8 + hd] + ad_d;
    uint2 v0 = *(const uint2*)(hp + (size_t)s0 * 256);
    uint2 v1 = *(const uint2*)(hp + (size_t)s1 * 256);
    uint2 v2 = *(const uint2*)(hp + (size_t)s2 * 256);
    uint2 v3 = *(const uint2*)(hp + (size_t)s3 * 256);
    float e0 = fexp2(fmaxf(l0, 0.2f * l0));
    float e1 = fexp2(fmaxf(l1, 0.2f * l1));
    float e2 = fexp2(fmaxf(l2, 0.2f * l2));
    float e3 = fexp2(fmaxf(l3, 0.2f * l3));
    half2v ep01 = pack2(e0, e1);
    half2v ep23 = pack2(e2, e3);
    denom = __builtin_amdgcn_fdot2(ep01, onepk, denom, false);
    denom = __builtin_amdgcn_fdot2(ep23, onepk, denom, false);
    uint32_t p;
    p = __builtin_amdgcn_perm(v1.x, v0.x, 0x05040100u);
    a0 = __builtin_amdgcn_fdot2(ep01, __builtin_bit_cast(half2v, p), a0, false);
    p = __builtin_amdgcn_perm(v1.x, v0.x, 0x07060302u);
    a1 = __builtin_amdgcn_fdot2(ep01, __builtin_bit_cast(half2v, p), a1, false);
    p = __builtin_amdgcn_perm(v1.y, v0.y, 0x05040100u);
    a2 = __builtin_amdgcn_fdot2(ep01, __builtin_bit_cast(half2v, p), a2, false);
    p = __builtin_amdgcn_perm(v1.y, v0.y, 0x07060302u);
    a3 = __builtin_amdgcn_fdot2(ep01, __builtin_bit_cast(half2v, p), a3, false);
    p = __builtin_amdgcn_perm(v3.x, v2.x, 0x05040100u);
    a0 = __builtin_amdgcn_fdot2(ep23, __builtin_bit_cast(half2v, p), a0, false);
    p = __builtin_amdgcn_perm(v3.x, v2.x, 0x07060302u);
    a1 = __builtin_amdgcn_fdot2(ep23, __builtin_bit_cast(half2v, p), a1, false);
    p = __builtin_amdgcn_perm(v3.y, v2.y, 0x05040100u);
    a2 = __builtin_amdgcn_fdot2(ep23, __builtin_bit_cast(half2v, p), a2, false);
    p = __builtin_amdgcn_perm(v3.y, v2.y, 0x07060302u);
    a3 = __builtin_amdgcn_fdot2(ep23, __builtin_bit_cast(half2v, p), a3, false);
  }
#endif
  for (; i < end; ++i) {
    int s = col_src[i];
    float l = as_[s * 8 + hd] + ad_d;
    float ev = fexp2(fmaxf(l, 0.2f * l));
    denom += ev;
    uint2 v = *(const uint2*)(hp + (size_t)s * 256);
    float2 p0 = h2x2(v.x), p1 = h2x2(v.y);
    a0 += ev * p0.x;
    a1 += ev * p0.y;
    a2 += ev * p1.x;
    a3 += ev * p1.y;
  }
  float inv = 1.f / (denom + 1e-16f);
  float v0 = a0 * inv + bias[c0 + 0];
  float v1 = a1 * inv + bias[c0 + 1];
  float v2 = a2 * inv + bias[c0 + 2];
  float v3 = a3 * inv + bias[c0 + 3];
  v0 = (v0 > 0.f) ? v0 : expm1f(v0);
  v1 = (v1 > 0.f) ? v1 : expm1f(v1);
  v2 = (v2 > 0.f) ? v2 : expm1f(v2);
  v3 = (v3 > 0.f) ? v3 : expm1f(v3);
  ushort4 hh;
  hh.x = f2h(v0); hh.y = f2h(v1); hh.z = f2h(v2); hh.w = f2h(v3);
  *(ushort4*)(of + (size_t)d * 256 + c0) = hh;
}

// Layer 3: fp16 h gather, 4 dst/wave (16 lanes x 4ch), fdot2 MAC, fp32 out.
__global__ __launch_bounds__(256) void aggr_f3(
    const int* __restrict__ rowptr, const int* __restrict__ col_src,
    const ushort* __restrict__ h, const float* __restrict__ as_,
    const float* __restrict__ ad_, const float* __restrict__ bias,
    float* __restrict__ outp, int n) {
  int wid = (blockIdx.x * 256 + threadIdx.x) >> 6;
  int d = wid * 4 + ((threadIdx.x >> 4) & 3);
  if (d >= n) return;
  int l = threadIdx.x & 15;
  int c0 = l * 4;
  float ad_d = ad_[d];
  float a0 = 0.f, a1 = 0.f, a2 = 0.f, a3 = 0.f, denom = 0.f;
  const ushort* hp = h + c0;
  int beg = rowptr[d], end = rowptr[d + 1];
  int i = beg;
#if USE_DOT2
  const half2v onepk = {(_Float16)1.f, (_Float16)1.f};
  for (; i + 2 <= end; i += 2) {
    int s0 = col_src[i], s1 = col_src[i + 1];
    float l0 = as_[s0] + ad_d;
    float l1 = as_[s1] + ad_d;
    uint2 v0 = *(const uint2*)(hp + (size_t)s0 * 64);
    uint2 v1 = *(const uint2*)(hp + (size_t)s1 * 64);
    float e0 = fexp2(fmaxf(l0, 0.2f * l0));
    float e1 = fexp2(fmaxf(l1, 0.2f * l1));
    half2v ep = pack2(e0, e1);
    denom = __builtin_amdgcn_fdot2(ep, onepk, denom, false);
    uint32_t p;
    p = __builtin_amdgcn_perm(v1.x, v0.x, 0x05040100u);
    a0 = __builtin_amdgcn_fdot2(ep, __builtin_bit_cast(half2v, p), a0, false);
    p = __builtin_amdgcn_perm(v1.x, v0.x, 0x07060302u);
    a1 = __builtin_amdgcn_fdot2(ep, __builtin_bit_cast(half2v, p), a1, false);
    p = __builtin_amdgcn_perm(v1.y, v0.y, 0x05040100u);
    a2 = __builtin_amdgcn_fdot2(ep, __builtin_bit_cast(half2v, p), a2, false);
    p = __builtin_amdgcn_perm(v1.y, v0.y, 0x07060302u);
    a3 = __builtin_amdgcn_fdot2(ep, __builtin_bit_cast(half2v, p), a3, false);
  }
#endif
  for (; i < end; ++i) {
    int s = col_src[i];
    float lg = as_[s] + ad_d;
    float ev = fexp2(fmaxf(lg, 0.2f * lg));
    denom += ev;
    uint2 v = *(const uint2*)(hp + (size_t)s * 64);
    float2 p0 = h2x2(v.x), p1 = h2x2(v.y);
    a0 += ev * p0.x;
    a1 += ev * p0.y;
    a2 += ev * p1.x;
    a3 += ev * p1.y;
  }
  float inv = 1.f / (denom + 1e-16f);
  float4 r;
  r.x = a0 * inv + bias[c0 + 0];
  r.y = a1 * inv + bias[c0 + 1];
  r.z = a2 * inv + bias[c0 + 2];
  r.w = a3 * inv + bias[c0 + 3];
  *(float4*)(outp + (size_t)d * 64 + c0) = r;
}

// ---------------------------------------------------------------------------

extern "C" void kernel_launch(void* const* d_in, const int* in_sizes, int n_in,
                              void* d_out, int out_size, void* d_ws, size_t ws_size,
                              hipStream_t stream) {
  const float* x   = (const float*)d_in[0];
  const int*   ei  = (const int*)d_in[1];
  const float* W1  = (const float*)d_in[2];
  const float* aS1 = (const float*)d_in[3];
  const float* aD1 = (const float*)d_in[4];
  const float* b1  = (const float*)d_in[5];
  const float* W2  = (const float*)d_in[6];
  const float* aS2 = (const float*)d_in[7];
  const float* aD2 = (const float*)d_in[8];
  const float* b2  = (const float*)d_in[9];
  const float* W3  = (const float*)d_in[10];
  const float* aS3 = (const float*)d_in[11];
  const float* aD3 = (const float*)d_in[12];
  const float* b3  = (const float*)d_in[13];

  const int* srcp = ei;
  const int* dstp = ei + NEDGES;

  // ---- arena (~72 MB) ----
  char* base = (char*)d_ws;
  size_t o = 0;
  ushort* hbf  = (ushort*)(base + o); o += 25600000;
  ushort* ff   = (ushort*)(base + o); o += 25600000;
  ushort* f1   = (ushort*)(base + o); o += 12800000;
  float*  as_  = (float*)(base + o);  o += 1600000;
  float*  ad_  = (float*)(base + o);  o += 1600000;
  ushort* w1t  = (ushort*)(base + o); o += 65536;
  ushort* w2t  = (ushort*)(base + o); o += 131072;
  ushort* w3t  = (ushort*)(base + o); o += 32768;
  int* rowptr  = (int*)(base + o);    o += 200016;
  int* cursor  = (int*)(base + o);    o += 200000;
  int* colsrc  = (int*)(base + o);    o += 3200000;
  int* bsum    = (int*)(base + o);    o += 1024;
  float* outp  = (float*)d_out;

  // ---- CSR build ----
  hipMemsetAsync(cursor, 0, NNODES * sizeof(int), stream);
  deg_kernel<<<(NEDGES + 255) / 256, 256, 0, stream>>>(dstp, cursor, NEDGES);
  int nb = (NNODES + 1023) / 1024;  // 49
  scan_partial<<<nb, 256, 0, stream>>>(cursor, rowptr, bsum, NNODES);
  scan_blocksums<<<1, 256, 0, stream>>>(bsum, nb);
  scan_add<<<(NNODES + 256) / 256, 256, 0, stream>>>(rowptr, bsum, cursor, NNODES, NEDGES);
  scatter_kernel<<<(NEDGES + 255) / 256, 256, 0, stream>>>(srcp, dstp, rowptr, cursor,
                                                           colsrc, NEDGES);

  // ---- conversions ----
  cvt_h<<<(NNODES * 128 / 4 + 255) / 256, 256, 0, stream>>>(x, f1, NNODES * 128 / 4);
  cvt_w<<<(128 * 256 + 255) / 256, 256, 0, stream>>>(W1, w1t, 128, 256);
  cvt_w<<<(256 * 256 + 255) / 256, 256, 0, stream>>>(W2, w2t, 256, 256);
  cvt_w<<<(256 * 64 + 255) / 256, 256, 0, stream>>>(W3, w3t, 256, 64);

  const int ga  = (NNODES + 3) / 4;
  const int ga4 = (NNODES + 15) / 16;
  const int gw  = (NNODES + 63) / 64;
  // ---- layer 1 ----
  gemm_wide<<<gw, 256, 0, stream>>>(f1, w1t, aS1, aD1, as_, ad_, hbf, NNODES, 128);
  aggr_h<<<ga, 256, 0, stream>>>(rowptr, colsrc, hbf, as_, ad_, b1, ff, NNODES);
  // ---- layer 2 ----
  gemm_wide<<<gw, 256, 0, stream>>>(ff, w2t, aS2, aD2, as_, ad_, hbf, NNODES, 256);
  aggr_h<<<ga, 256, 0, stream>>>(rowptr, colsrc, hbf, as_, ad_, b2, ff, NNODES);
  // ---- layer 3 ----
  gemm_mfma3<<<dim3(1, (NNODES + 127) / 128), 256, 0, stream>>>(
      ff, w3t, aS3, aD3, as_, ad_, hbf, NNODES, 256, 64);
  aggr_f3<<<ga4, 256, 0, stream>>>(rowptr, colsrc, hbf, as_, ad_, b3, outp, NNODES);
}